// Round 13
// baseline (598.970 us; speedup 1.0000x reference)
//
#include <hip/hip_runtime.h>
#include <math.h>

#define CH    64
#define WW    192
#define HH    192
#define HWSZ  (192*192)
#define KK    49
#define SROW  72   // f16 row stride in shorts (144B)
#define C3ROW 72   // conv3 staged px stride (shorts)
#define OROW  136  // k_out staged px stride (shorts, 128ch + 8 pad)
#define REDW  20   // reduction row stride (floats): 80B, 16B-aligned
#define GRID  768

typedef __attribute__((ext_vector_type(8))) short     s16x8;
typedef __attribute__((ext_vector_type(8))) _Float16  h16x8;  // 8 f16 = 4 VGPR
typedef __attribute__((ext_vector_type(2))) _Float16  h16x2;
typedef __attribute__((ext_vector_type(2))) __fp16    fp16x2; // cvt_pkrtz result type
typedef __attribute__((ext_vector_type(4))) float     f32x4;

__device__ __forceinline__ unsigned short f2h(float f) {
    union { _Float16 h; unsigned short s; } u; u.h = (_Float16)f;  // RNE
    return u.s;
}

__device__ __forceinline__ float h2f(unsigned short s) {
    union { unsigned short s; _Float16 h; } u; u.s = s;
    return (float)u.h;
}

// pack two floats to f16x2 (RTZ, single v_cvt_pkrtz_f16_f32)
__device__ __forceinline__ unsigned pkh(float lo, float hi) {
    union { fp16x2 h; unsigned u; } v;
    v.h = __builtin_amdgcn_cvt_pkrtz(lo, hi);
    return v.u;
}

// broadcast one float into packed f16x2 (for pk_fma weights)
__device__ __forceinline__ h16x2 cvt2h(float a) {
    union { fp16x2 h; h16x2 o; } v;
    v.h = __builtin_amdgcn_cvt_pkrtz(a, a);
    return v.o;
}

__device__ __forceinline__ h16x2 as_h2(unsigned u) {
    union { unsigned u; h16x2 h; } v; v.u = u; return v.h;
}

__device__ __forceinline__ unsigned as_u(h16x2 h) {
    union { h16x2 h; unsigned u; } v; v.h = h; return v.u;
}

__device__ const float c_cos8[8] = {
    1.f, 0.70710678118654752f, 0.f, -0.70710678118654752f,
   -1.f, -0.70710678118654752f, 0.f, 0.70710678118654752f };

// ---------------------------------------------------------------------------
// Hand-rolled grid barrier: plain launch + workspace atomic counter.
// Co-residency: LDS 32768 -> 5 blocks/CU; launch_bounds(256,4) -> VGPR<=128
// -> 4 blocks/CU -> 1024 block slots; GRID=768 leaves 25% slack.
// Counters zeroed via hipMemsetAsync on the stream before launch.
// ---------------------------------------------------------------------------
__device__ __forceinline__ void gbar(int* cnt) {
    __threadfence();                    // release: my writes visible agent-wide
    __syncthreads();
    if (threadIdx.x == 0) {
        atomicAdd(cnt, 1);
        while (atomicAdd(cnt, 0) < GRID) __builtin_amdgcn_s_sleep(32);
    }
    __syncthreads();
    __threadfence();                    // acquire: see others' writes
}

// ---------------------------------------------------------------------------
// k_all: single plain launch, 768 blocks x 256.
// Phase A: pt (trans 576 + prep 49; 625 < 768 direct). gbar.
// Phase B: dff (2304 deform + 576 fft units, grid-stride 768). gbar.
// Phase C: c3out (576 < 768 direct).
// ---------------------------------------------------------------------------
__global__ __launch_bounds__(256, 4) void k_all(
    const float* __restrict__ enc,
    unsigned short* __restrict__ encH,
    const float* __restrict__ fw,
    const float* __restrict__ wd,
    const float* __restrict__ w2,
    const float* __restrict__ wc1,
    const float* __restrict__ wpo,
    const float* __restrict__ wpi,
    float* __restrict__ krT,
    short* __restrict__ wA,
    short* __restrict__ w2A,
    short* __restrict__ wpoA,
    short* __restrict__ wpiA,
    const float* __restrict__ off,
    const float* __restrict__ msk,
    unsigned short* __restrict__ revH,
    unsigned short* __restrict__ e1H,
    const float* __restrict__ dec,
    float* __restrict__ out,
    int* gcnt)
{
    __shared__ __align__(16) char smem_raw[32768];
    int b = blockIdx.x;                 // 0..767
    int t = threadIdx.x;
    int lane = t & 63, w = t >> 6;

    // ===================== Phase A: pt =====================
    if (b < 576) {
        // ---- trans: enc fp32 [c][p] -> encH f16 [p][c] ----
        float* s = (float*)smem_raw;    // 64*65 floats = 16640 B
        int base = b * 64;
#pragma unroll
        for (int r = 0; r < 16; r++) {
            int idx = t + r * 256;
            int p = idx & 63, c = idx >> 6;
            s[p * 65 + c] = enc[c * HWSZ + base + p];
        }
        __syncthreads();
#pragma unroll
        for (int r = 0; r < 8; r++) {
            int idx = t + r * 256;             // 2048 pair-units
            int pr = idx & 31, p = idx >> 5;   // pair 0..31, px 0..63
            ((unsigned*)encH)[(base + p) * 32 + pr] =
                pkh(s[p * 65 + 2 * pr], s[p * 65 + 2 * pr + 1]);
        }
    } else if (b < 625) {
        // ---- prep: krT + A-frag packs ----
        int kb = b - 576;                      // 0..48
        int tid = kb * 256 + t;
        int nt  = 49 * 256;
        for (int u = tid; u < 64 * 64; u += nt) {
            int uv = u >> 6, c = u & 63;
            int uu = uv >> 3, v = uv & 7;
            float acc = 0.f;
            for (int ky = 0; ky < 8; ky++)
                for (int kx = 0; kx < 8; kx++) {
                    float wv = (kx <= 4) ? fw[c * 40 + ky * 5 + kx]
                                         : fw[c * 40 + ((8 - ky) & 7) * 5 + (8 - kx)];
                    acc += wv * c_cos8[(ky * uu + kx * v) & 7];
                }
            krT[uv * 64 + c] = acc * (1.f / 64.f);
        }
        for (int u = tid; u < 9 * 4096; u += nt) {
            int tap = u / 4096, rem = u & 4095;
            int o = rem >> 6, c = rem & 63;
            float v = w2[(o * 64 + c) * 9 + tap];
            int fi = tap * 8 + (o >> 4) * 2 + (c >> 5);
            int ln = ((c >> 3) & 3) * 16 + (o & 15);
            w2A[fi * 512 + ln * 8 + (c & 7)] = (short)f2h(v);
        }
        for (int u = tid; u < 128 * 128; u += nt) {
            int o = u >> 7, c = u & 127;
            int fi = (o >> 4) * 4 + (c >> 5);
            int ln = ((c >> 3) & 3) * 16 + (o & 15);
            wpoA[fi * 512 + ln * 8 + (c & 7)] = (short)f2h(wpo[u]);
        }
        for (int u = tid; u < 64 * 64; u += nt) {
            int o = u >> 6, c = u & 63;
            int fi = (o >> 4) * 2 + (c >> 5);
            int ln = ((c >> 3) & 3) * 16 + (o & 15);
            wpiA[fi * 512 + ln * 8 + (c & 7)] = (short)f2h(wpi[u]);
        }

        // ---- fold wc1 @ wd + pack: one block per tap kb ----
        // PROW=64 (no pad): fits 32768 B; conflicts irrelevant (runs once)
        float* wdk  = (float*)smem_raw;        // 4096 floats
        float* wc1s = wdk + 4096;              // 4096 floats
#pragma unroll
        for (int r = 0; r < 16; r++) {
            int idx = t + r * 256;
            int o = idx >> 6, c = idx & 63;
            wdk [o * 64 + c] = wd[(o * 64 + c) * KK + kb];
            wc1s[o * 64 + c] = wc1[o * 64 + c];
        }
        __syncthreads();

        int ot = (t >> 4) * 4, cb = (t & 15) * 4;
        float a[4][4];
#pragma unroll
        for (int i = 0; i < 4; i++)
#pragma unroll
            for (int j = 0; j < 4; j++) a[i][j] = 0.f;
        for (int o = 0; o < 64; o++) {
            float wv_[4], sv_[4];
#pragma unroll
            for (int i = 0; i < 4; i++) wv_[i] = wc1s[(ot + i) * 64 + o];
#pragma unroll
            for (int j = 0; j < 4; j++) sv_[j] = wdk[o * 64 + cb + j];
#pragma unroll
            for (int i = 0; i < 4; i++)
#pragma unroll
                for (int j = 0; j < 4; j++) a[i][j] += wv_[i] * sv_[j];
        }
#pragma unroll
        for (int i = 0; i < 4; i++)
#pragma unroll
            for (int j = 0; j < 4; j++) {
                int o2 = ot + i, c = cb + j;
                int tt = o2 >> 4, m = o2 & 15;
                int kt = c >> 5, q2 = (c >> 3) & 3, jj = c & 7;
                int ln = q2 * 16 + m;
                wA[(kb * 8 + tt * 2 + kt) * 512 + ln * 8 + jj] = (short)f2h(a[i][j]);
            }
    }

    gbar(gcnt + 0);

    // ===================== Phase B: dff (grid-stride) =====================
#pragma unroll 1
    for (int ub = b; ub < 2880; ub += GRID) {
        __syncthreads();   // protect LDS reuse across units
        if (ub < 2304) {
            // ---------------- deform unit ----------------
            short* sm_base = (short*)smem_raw;                   // 4 x 16*SROW shorts
            float* red = (float*)(smem_raw + 4 * 16 * SROW * 2); // 2*64*REDW floats

            int xcd = ub & 7, blk = ub >> 3;
            int gy  = xcd * 24 + blk / 12;
            int gx0 = (blk % 12) * 16;

            int sp = lane >> 2, g = lane & 3;
            int sgx  = gx0 + sp;
            int gp_s = gy * WW + sgx;
            int n = lane & 15, q = lane >> 4;
            short* smw = sm_base + w * (16 * SROW);

            f32x4 acc[4];
#pragma unroll
            for (int ot = 0; ot < 4; ot++) acc[ot] = (f32x4){0.f, 0.f, 0.f, 0.f};

            int kstart = (w == 0) ? 0 : 13 + (w - 1) * 12;
            int kend   = (w == 0) ? 13 : kstart + 12;

            float dy = off[(2 * kstart) * HWSZ + gp_s];
            float dx = off[(2 * kstart + 1) * HWSZ + gp_s];
            float mm = msk[kstart * HWSZ + gp_s];

#pragma unroll 1
            for (int k = kstart; k < kend; k++) {
                int ky = k / 7, kx = k % 7;
                float y = (float)(gy  - 3 + ky) + dy;
                float x = (float)(sgx - 3 + kx) + dx;
                float y0f = floorf(y), x0f = floorf(x);
                float wy = y - y0f, wx = x - x0f;
                int iy0 = (int)y0f, ix0 = (int)x0f;
                int iy1 = iy0 + 1, ix1 = ix0 + 1;
                bool vy0 = (iy0 >= 0) & (iy0 < HH);
                bool vy1 = (iy1 >= 0) & (iy1 < HH);
                bool vx0 = (ix0 >= 0) & (ix0 < WW);
                bool vx1 = (ix1 >= 0) & (ix1 < WW);
                int iy0c = min(max(iy0, 0), HH - 1), iy1c = min(max(iy1, 0), HH - 1);
                int ix0c = min(max(ix0, 0), WW - 1), ix1c = min(max(ix1, 0), WW - 1);
                float a00 = (vy0 & vx0) ? (1.f - wy) * (1.f - wx) * mm : 0.f;
                float a01 = (vy0 & vx1) ? (1.f - wy) * wx * mm : 0.f;
                float a10 = (vy1 & vx0) ? wy * (1.f - wx) * mm : 0.f;
                float a11 = (vy1 & vx1) ? wy * wx * mm : 0.f;

                const unsigned short* b00p = encH + (iy0c * WW + ix0c) * 64 + g * 16;
                const unsigned short* b01p = encH + (iy0c * WW + ix1c) * 64 + g * 16;
                const unsigned short* b10p = encH + (iy1c * WW + ix0c) * 64 + g * 16;
                const unsigned short* b11p = encH + (iy1c * WW + ix1c) * 64 + g * 16;
                uint4 u00[2], u01[2], u10[2], u11[2];
                u00[0] = *(const uint4*)b00p;  u00[1] = *(const uint4*)(b00p + 8);
                u01[0] = *(const uint4*)b01p;  u01[1] = *(const uint4*)(b01p + 8);
                u10[0] = *(const uint4*)b10p;  u10[1] = *(const uint4*)(b10p + 8);
                u11[0] = *(const uint4*)b11p;  u11[1] = *(const uint4*)(b11p + 8);

                float dyn = 0.f, dxn = 0.f, mmn = 0.f;
                if (k + 1 < kend) {
                    dyn = off[(2 * k + 2) * HWSZ + gp_s];
                    dxn = off[(2 * k + 3) * HWSZ + gp_s];
                    mmn = msk[(k + 1) * HWSZ + gp_s];
                }

                h16x8 af[8];
#pragma unroll
                for (int f = 0; f < 8; f++)
                    af[f] = *(const h16x8*)&wA[(k * 8 + f) * 512 + lane * 8];

                h16x2 w00 = cvt2h(a00);
                h16x2 w01 = cvt2h(a01);
                h16x2 w10 = cvt2h(a10);
                h16x2 w11 = cvt2h(a11);

                unsigned c00[8] = {u00[0].x, u00[0].y, u00[0].z, u00[0].w,
                                   u00[1].x, u00[1].y, u00[1].z, u00[1].w};
                unsigned c01[8] = {u01[0].x, u01[0].y, u01[0].z, u01[0].w,
                                   u01[1].x, u01[1].y, u01[1].z, u01[1].w};
                unsigned c10[8] = {u10[0].x, u10[0].y, u10[0].z, u10[0].w,
                                   u10[1].x, u10[1].y, u10[1].z, u10[1].w};
                unsigned c11[8] = {u11[0].x, u11[0].y, u11[0].z, u11[0].w,
                                   u11[1].x, u11[1].y, u11[1].z, u11[1].w};
                unsigned pk[8];
#pragma unroll
                for (int j = 0; j < 8; j++) {
                    h16x2 r = as_h2(c00[j]) * w00;
                    r = as_h2(c01[j]) * w01 + r;
                    r = as_h2(c10[j]) * w10 + r;
                    r = as_h2(c11[j]) * w11 + r;
                    pk[j] = as_u(r);
                }
                *(uint4*)&smw[sp * SROW + g * 16]     = make_uint4(pk[0], pk[1], pk[2], pk[3]);
                *(uint4*)&smw[sp * SROW + g * 16 + 8] = make_uint4(pk[4], pk[5], pk[6], pk[7]);

                h16x8 b0 = *(const h16x8*)&smw[n * SROW +  0 + q * 8];
                h16x8 b1 = *(const h16x8*)&smw[n * SROW + 32 + q * 8];

#pragma unroll
                for (int ot = 0; ot < 4; ot++) {
                    acc[ot] = __builtin_amdgcn_mfma_f32_16x16x32_f16(af[ot * 2],     b0, acc[ot], 0, 0, 0);
                    acc[ot] = __builtin_amdgcn_mfma_f32_16x16x32_f16(af[ot * 2 + 1], b1, acc[ot], 0, 0, 0);
                }

                dy = dyn; dx = dxn; mm = mmn;
            }

            // two-phase tree reduction (2-slot buffer)
            if (w >= 2) {
                float* rp = &red[((w - 2) * 64 + lane) * REDW];
#pragma unroll
                for (int ot = 0; ot < 4; ot++)
                    *(float4*)&rp[ot * 4] = make_float4(acc[ot][0], acc[ot][1], acc[ot][2], acc[ot][3]);
            }
            __syncthreads();
            if (w < 2) {
                const float* rp = &red[(w * 64 + lane) * REDW];
#pragma unroll
                for (int ot = 0; ot < 4; ot++) {
                    float4 v = *(const float4*)&rp[ot * 4];
                    acc[ot][0] += v.x; acc[ot][1] += v.y;
                    acc[ot][2] += v.z; acc[ot][3] += v.w;
                }
            }
            __syncthreads();
            if (w == 1) {
                float* rp = &red[lane * REDW];
#pragma unroll
                for (int ot = 0; ot < 4; ot++)
                    *(float4*)&rp[ot * 4] = make_float4(acc[ot][0], acc[ot][1], acc[ot][2], acc[ot][3]);
            }
            __syncthreads();
            if (w == 0) {
                const float* rp = &red[lane * REDW];
#pragma unroll
                for (int ot = 0; ot < 4; ot++) {
                    float4 v = *(const float4*)&rp[ot * 4];
                    acc[ot][0] += v.x; acc[ot][1] += v.y;
                    acc[ot][2] += v.z; acc[ot][3] += v.w;
                }
                int gp_m = gy * WW + gx0 + n;
#pragma unroll
                for (int ot = 0; ot < 4; ot++) {
                    unsigned u0 = pkh(acc[ot][0], acc[ot][1]);
                    unsigned u1 = pkh(acc[ot][2], acc[ot][3]);
                    *(uint2*)&revH[gp_m * 64 + ot * 16 + q * 4] = make_uint2(u0, u1);
                }
            }
        } else {
            // ---------------- fft unit ----------------
            short* sbf = (short*)smem_raw;                   // 9216 B
            short* e0H = (short*)(smem_raw + 64 * SROW * 2); // 9216 B

            int pb = ub - 2304;
            int pbx = pb % 24, pby = pb / 24;
            int gx0 = pbx * 8, gy0 = pby * 8;

#pragma unroll
            for (int r = 0; r < 2; r++) {
                int idx = t + r * 256;             // 512 x 8-ch units
                int px = idx >> 3, g8 = idx & 7;
                int gy = gy0 + (px >> 3), gx = gx0 + (px & 7);
                *(uint4*)&sbf[px * SROW + g8 * 8] =
                    *(const uint4*)&encH[(gy * WW + gx) * 64 + g8 * 8];
            }
            __syncthreads();

            int n = lane & 15, q = lane >> 4;
            h16x8 a0 = *(const h16x8*)&wpiA[(w * 2 + 0) * 512 + lane * 8];
            h16x8 a1 = *(const h16x8*)&wpiA[(w * 2 + 1) * 512 + lane * 8];
#pragma unroll
            for (int j = 0; j < 4; j++) {
                h16x8 b0 = *(const h16x8*)&sbf[(j * 16 + n) * SROW +  0 + q * 8];
                h16x8 b1 = *(const h16x8*)&sbf[(j * 16 + n) * SROW + 32 + q * 8];
                f32x4 acc = {0.f, 0.f, 0.f, 0.f};
                acc = __builtin_amdgcn_mfma_f32_16x16x32_f16(a0, b0, acc, 0, 0, 0);
                acc = __builtin_amdgcn_mfma_f32_16x16x32_f16(a1, b1, acc, 0, 0, 0);
                unsigned u0 = pkh(acc[0], acc[1]);
                unsigned u1 = pkh(acc[2], acc[3]);
                *(unsigned*)&e0H[(j * 16 + n) * SROW + w * 16 + q * 4]     = u0;
                *(unsigned*)&e0H[(j * 16 + n) * SROW + w * 16 + q * 4 + 2] = u1;
            }
            __syncthreads();

            int o = t & 63;
            int yb = t >> 6;
#pragma unroll
            for (int yy = 0; yy < 2; yy++) {
                int y = yb + yy * 4;
                float outr[8];
#pragma unroll
                for (int x = 0; x < 8; x++) outr[x] = 0.f;
#pragma unroll
                for (int u = 0; u < 8; u++) {
                    int ry = (y - u + 8) & 7;
                    float row[8];
#pragma unroll
                    for (int rx = 0; rx < 8; rx++)
                        row[rx] = h2f(((const unsigned short*)e0H)[(ry * 8 + rx) * SROW + o]);
#pragma unroll
                    for (int v = 0; v < 8; v++) {
                        float kv = krT[(u * 8 + v) * 64 + o];
#pragma unroll
                        for (int x = 0; x < 8; x++)
                            outr[x] += kv * row[(x - v + 8) & 7];
                    }
                }
                int gy = gy0 + y;
#pragma unroll
                for (int x = 0; x < 8; x++)
                    e1H[(gy * WW + gx0 + x) * 64 + o] = f2h(outr[x]);
            }
        }
    }

    gbar(gcnt + 1);

    // ===================== Phase C: c3out =====================
    if (b < 576) {
        short* sm = (short*)smem_raw;          // 4 x 54*C3ROW shorts = 31104 B
        int xcd = b & 7, blk = b >> 3;
        int gy  = xcd * 24 + blk / 3;
        int gx0 = (blk % 3) * 64 + w * 16;
        short* smw = sm + w * (54 * C3ROW);
        int n = lane & 15, q = lane >> 4;

        for (int r = 0; r < 14; r++) {
            int u = lane + r * 64;
            if (u < 864) {
                int rp = u >> 4, g = u & 15;
                int row = rp / 18, pxl = rp - row * 18;
                int gyy = gy + row - 1, gxx = gx0 + pxl - 1;
                uint2 v = make_uint2(0u, 0u);
                if (gyy >= 0 && gyy < HH && gxx >= 0 && gxx < WW) {
                    int gp = (gyy * WW + gxx) * 64 + g * 4;    // short index
                    uint2 va = *(const uint2*)&e1H[gp];
                    uint2 vb = *(const uint2*)&revH[gp];
                    v.x = as_u(as_h2(va.x) + as_h2(vb.x));
                    v.y = as_u(as_h2(va.y) + as_h2(vb.y));
                }
                *(uint2*)&smw[rp * C3ROW + g * 4] = v;
            }
        }

        f32x4 acc[4];
#pragma unroll
        for (int ot = 0; ot < 4; ot++) acc[ot] = (f32x4){0.f, 0.f, 0.f, 0.f};

#pragma unroll 1
        for (int tap = 0; tap < 9; tap++) {
            int dy = tap / 3, dx = tap - dy * 3;
            int rp = dy * 18 + n + dx;
            h16x8 b0 = *(const h16x8*)&smw[rp * C3ROW +  0 + q * 8];
            h16x8 b1 = *(const h16x8*)&smw[rp * C3ROW + 32 + q * 8];
#pragma unroll
            for (int ot = 0; ot < 4; ot++) {
                h16x8 a0 = *(const h16x8*)&w2A[(tap * 8 + ot * 2 + 0) * 512 + lane * 8];
                h16x8 a1 = *(const h16x8*)&w2A[(tap * 8 + ot * 2 + 1) * 512 + lane * 8];
                acc[ot] = __builtin_amdgcn_mfma_f32_16x16x32_f16(a0, b0, acc[ot], 0, 0, 0);
                acc[ot] = __builtin_amdgcn_mfma_f32_16x16x32_f16(a1, b1, acc[ot], 0, 0, 0);
            }
        }

        // fused proj_out: stage e3 (C-layout regs) + dec into B-frag rows
#pragma unroll
        for (int ot = 0; ot < 4; ot++) {
            unsigned lo = pkh(acc[ot][0], acc[ot][1]);
            unsigned hi = pkh(acc[ot][2], acc[ot][3]);
            *(uint2*)&smw[n * OROW + ot * 16 + q * 4] = make_uint2(lo, hi);
        }
        {
            int gp = gy * WW + gx0 + n;
            unsigned pk[8];
#pragma unroll
            for (int i = 0; i < 8; i++) {
                float va = dec[(q * 16 + 2 * i)     * HWSZ + gp];
                float vb = dec[(q * 16 + 2 * i + 1) * HWSZ + gp];
                pk[i] = pkh(va, vb);
            }
            *(uint4*)&smw[n * OROW + 64 + q * 16]     = make_uint4(pk[0], pk[1], pk[2], pk[3]);
            *(uint4*)&smw[n * OROW + 64 + q * 16 + 8] = make_uint4(pk[4], pk[5], pk[6], pk[7]);
        }

        f32x4 go[8];
#pragma unroll
        for (int ot = 0; ot < 8; ot++) go[ot] = (f32x4){0.f, 0.f, 0.f, 0.f};

#pragma unroll 1
        for (int kt = 0; kt < 4; kt++) {
            h16x8 bb = *(const h16x8*)&smw[n * OROW + kt * 32 + q * 8];
#pragma unroll
            for (int ot = 0; ot < 8; ot++) {
                h16x8 aa = *(const h16x8*)&wpoA[(ot * 4 + kt) * 512 + lane * 8];
                go[ot] = __builtin_amdgcn_mfma_f32_16x16x32_f16(aa, bb, go[ot], 0, 0, 0);
            }
        }

        int gp = gy * WW + gx0 + n;
#pragma unroll
        for (int ot = 0; ot < 4; ot++)
#pragma unroll
            for (int r = 0; r < 4; r++)
                out[(ot * 16 + q * 4 + r) * HWSZ + gp] = go[ot][r] * go[ot + 4][r];
    }
}

// ---------------------------------------------------------------------------
extern "C" void kernel_launch(void* const* d_in, const int* in_sizes, int n_in,
                              void* d_out, int out_size, void* d_ws, size_t ws_size,
                              hipStream_t stream)
{
    const float* enc  = (const float*)d_in[0];
    const float* dec  = (const float*)d_in[1];
    const float* ioff = (const float*)d_in[2];
    const float* iwt  = (const float*)d_in[3];
    const float* wpi  = (const float*)d_in[4];
    const float* fw   = (const float*)d_in[5];
    const float* wpo  = (const float*)d_in[6];
    const float* wd   = (const float*)d_in[7];
    const float* wc1  = (const float*)d_in[8];
    const float* wc2  = (const float*)d_in[9];
    float* out = (float*)d_out;
    float* ws  = (float*)d_ws;

    float*          krT  = ws;                               //   4096 fl
    unsigned short* revH = (unsigned short*)(ws + 4096);     // 2359296 sh
    unsigned short* e1H  = (unsigned short*)(ws + 1183744);  // 2359296 sh
    unsigned short* encH = (unsigned short*)(ws + 2363392);  // 2359296 sh
    short*          wA   = (short*)(ws + 3543040);           // 200704 sh
    short*          w2A  = (short*)(ws + 3643392);           //  36864 sh
    short*          wpoA = (short*)(ws + 3661824);           //  16384 sh
    short*          wpiA = (short*)(ws + 3670016);           //   4096 sh
    int*            gcnt = (int*)(ws + 3680000);             //   2 ints (barrier)

    hipMemsetAsync(gcnt, 0, 2 * sizeof(int), stream);
    hipLaunchKernelGGL(k_all, dim3(GRID), dim3(256), 0, stream,
                       enc, encH, fw, wd, wc2, wc1, wpo, wpi, krT, wA,
                       w2A, wpoA, wpiA, ioff, iwt, revH, e1H, dec, out, gcnt);
}

// Round 14
// 187.537 us; speedup vs baseline: 3.1939x; 3.1939x over previous
//
#include <hip/hip_runtime.h>
#include <math.h>

#define CH    64
#define WW    192
#define HH    192
#define HWSZ  (192*192)
#define KK    49
#define ROWP  68   // padded fp32 LDS row (dwords)
#define SROW  72   // f16 row stride in shorts (144B)
#define C3ROW 72   // conv3 staged px stride (shorts)
#define OROW  136  // k_out staged px stride (shorts)
#define REDW  20   // reduction row stride (floats): 80B, 16B-aligned

typedef __attribute__((ext_vector_type(8))) short     s16x8;
typedef __attribute__((ext_vector_type(8))) _Float16  h16x8;  // 8 f16 = 4 VGPR
typedef __attribute__((ext_vector_type(2))) _Float16  h16x2;
typedef __attribute__((ext_vector_type(2))) __fp16    fp16x2; // cvt_pkrtz result type
typedef __attribute__((ext_vector_type(4))) float     f32x4;

__device__ __forceinline__ unsigned short f2h(float f) {
    union { _Float16 h; unsigned short s; } u; u.h = (_Float16)f;  // RNE
    return u.s;
}

__device__ __forceinline__ float h2f(unsigned short s) {
    union { unsigned short s; _Float16 h; } u; u.s = s;
    return (float)u.h;
}

// pack two floats to f16x2 (RTZ, single v_cvt_pkrtz_f16_f32)
__device__ __forceinline__ unsigned pkh(float lo, float hi) {
    union { fp16x2 h; unsigned u; } v;
    v.h = __builtin_amdgcn_cvt_pkrtz(lo, hi);
    return v.u;
}

// broadcast one float into packed f16x2 (for pk_fma weights)
__device__ __forceinline__ h16x2 cvt2h(float a) {
    union { fp16x2 h; h16x2 o; } v;
    v.h = __builtin_amdgcn_cvt_pkrtz(a, a);
    return v.o;
}

__device__ __forceinline__ h16x2 as_h2(unsigned u) {
    union { unsigned u; h16x2 h; } v; v.u = u; return v.h;
}

__device__ __forceinline__ unsigned as_u(h16x2 h) {
    union { h16x2 h; unsigned u; } v; v.h = h; return v.u;
}

// ---------------------------------------------------------------------------
// k_pt (grid 625): b<576 -> trans (enc fp32 [c][p] -> encH f16 [p][c]);
// b>=576 -> prep tap k=b-576 (krT + A-frag packs).
// ---------------------------------------------------------------------------
__device__ const float c_cos8[8] = {
    1.f, 0.70710678118654752f, 0.f, -0.70710678118654752f,
   -1.f, -0.70710678118654752f, 0.f, 0.70710678118654752f };

__global__ __launch_bounds__(256) void k_pt(
    const float* __restrict__ enc,  // trans input
    unsigned short* __restrict__ encH,
    const float* __restrict__ fw,   // [64,1,1,8,5]
    const float* __restrict__ wd,   // [64,64,7,7]
    const float* __restrict__ w2,   // [64,64,3,3]
    const float* __restrict__ wc1,  // [64,64,1,1]
    const float* __restrict__ wpo,  // [128,128]
    const float* __restrict__ wpi,  // [64,64]
    float* __restrict__ krT,        // [64 uv][64 c]
    short* __restrict__ wA,         // [49*8*512]
    short* __restrict__ w2A,        // [9*8*512]
    short* __restrict__ wpoA,       // [32*512]
    short* __restrict__ wpiA)       // [8*512]
{
    __shared__ __align__(16) char smem_raw[2 * 64 * ROWP * 4];  // 34816 B
    int b = blockIdx.x;
    int t = threadIdx.x;

    if (b < 576) {
        // ---- trans ----
        float* s = (float*)smem_raw;           // 64*65 floats = 16640 B
        int base = b * 64;
#pragma unroll
        for (int r = 0; r < 16; r++) {
            int idx = t + r * 256;
            int p = idx & 63, c = idx >> 6;
            s[p * 65 + c] = enc[c * HWSZ + base + p];
        }
        __syncthreads();
#pragma unroll
        for (int r = 0; r < 8; r++) {
            int idx = t + r * 256;             // 2048 pair-units
            int pr = idx & 31, p = idx >> 5;   // pair 0..31, px 0..63
            ((unsigned*)encH)[(base + p) * 32 + pr] =
                pkh(s[p * 65 + 2 * pr], s[p * 65 + 2 * pr + 1]);
        }
        return;
    }

    // ---- prep ----
    int kb = b - 576;                          // 0..48
    int tid = kb * 256 + t;
    int nt  = 49 * 256;
    for (int u = tid; u < 64 * 64; u += nt) {
        int uv = u >> 6, c = u & 63;
        int uu = uv >> 3, v = uv & 7;
        float acc = 0.f;
        for (int ky = 0; ky < 8; ky++)
            for (int kx = 0; kx < 8; kx++) {
                float wv = (kx <= 4) ? fw[c * 40 + ky * 5 + kx]
                                     : fw[c * 40 + ((8 - ky) & 7) * 5 + (8 - kx)];
                acc += wv * c_cos8[(ky * uu + kx * v) & 7];
            }
        krT[uv * 64 + c] = acc * (1.f / 64.f);
    }
    for (int u = tid; u < 9 * 4096; u += nt) {
        int tap = u / 4096, rem = u & 4095;
        int o = rem >> 6, c = rem & 63;
        float v = w2[(o * 64 + c) * 9 + tap];
        int fi = tap * 8 + (o >> 4) * 2 + (c >> 5);
        int ln = ((c >> 3) & 3) * 16 + (o & 15);
        w2A[fi * 512 + ln * 8 + (c & 7)] = (short)f2h(v);
    }
    for (int u = tid; u < 128 * 128; u += nt) {
        int o = u >> 7, c = u & 127;
        int fi = (o >> 4) * 4 + (c >> 5);
        int ln = ((c >> 3) & 3) * 16 + (o & 15);
        wpoA[fi * 512 + ln * 8 + (c & 7)] = (short)f2h(wpo[u]);
    }
    for (int u = tid; u < 64 * 64; u += nt) {
        int o = u >> 6, c = u & 63;
        int fi = (o >> 4) * 2 + (c >> 5);
        int ln = ((c >> 3) & 3) * 16 + (o & 15);
        wpiA[fi * 512 + ln * 8 + (c & 7)] = (short)f2h(wpi[u]);
    }

    // ---- fold wc1 @ wd + pack: one block per tap kb ----
    float* wdk  = (float*)smem_raw;            // 64*ROWP floats
    float* wc1s = wdk + 64 * ROWP;             // 64*ROWP floats
#pragma unroll
    for (int r = 0; r < 16; r++) {
        int idx = t + r * 256;
        int o = idx >> 6, c = idx & 63;
        wdk [o * ROWP + c] = wd[(o * 64 + c) * KK + kb];
        wc1s[o * ROWP + c] = wc1[o * 64 + c];
    }
    __syncthreads();

    int ot = (t >> 4) * 4, cb = (t & 15) * 4;
    float a[4][4];
#pragma unroll
    for (int i = 0; i < 4; i++)
#pragma unroll
        for (int j = 0; j < 4; j++) a[i][j] = 0.f;
    for (int o = 0; o < 64; o++) {
        float wv_[4], sv_[4];
#pragma unroll
        for (int i = 0; i < 4; i++) wv_[i] = wc1s[(ot + i) * ROWP + o];
#pragma unroll
        for (int j = 0; j < 4; j++) sv_[j] = wdk[o * ROWP + cb + j];
#pragma unroll
        for (int i = 0; i < 4; i++)
#pragma unroll
            for (int j = 0; j < 4; j++) a[i][j] += wv_[i] * sv_[j];
    }
#pragma unroll
    for (int i = 0; i < 4; i++)
#pragma unroll
        for (int j = 0; j < 4; j++) {
            int o2 = ot + i, c = cb + j;
            int tt = o2 >> 4, m = o2 & 15;
            int kt = c >> 5, q2 = (c >> 3) & 3, jj = c & 7;
            int ln = q2 * 16 + m;
            wA[(kb * 8 + tt * 2 + kt) * 512 + ln * 8 + jj] = (short)f2h(a[i][j]);
        }
}

// ---------------------------------------------------------------------------
// k_dff (grid 2880): b<2304 -> deform (R12 structure); b>=2304 -> fft.
// rev and e1 written f16 [px][64].
// ---------------------------------------------------------------------------
__global__ __launch_bounds__(256) void k_dff(
    const unsigned short* __restrict__ encH, const float* __restrict__ off,
    const float* __restrict__ msk, const short* __restrict__ wA,
    unsigned short* __restrict__ revH,
    const short* __restrict__ wpiA, const float* __restrict__ krT,
    unsigned short* __restrict__ e1H)
{
    __shared__ __align__(16) char smem_raw[19456];
    int t = threadIdx.x;
    int lane = t & 63, w = t >> 6;
    int b = blockIdx.x;

    if (b < 2304) {
        // ================= deform =================
        short* sm_base = (short*)smem_raw;                 // 4 x 16*SROW shorts
        float* red = (float*)(smem_raw + 4 * 16 * SROW * 2); // 2*64*REDW floats

        int xcd = b & 7, blk = b >> 3;          // 288 strips per xcd band
        int gy  = xcd * 24 + blk / 12;
        int gx0 = (blk % 12) * 16;

        int sp = lane >> 2, g = lane & 3;       // gather map: quad-coalesced
        int sgx  = gx0 + sp;
        int gp_s = gy * WW + sgx;
        int n = lane & 15, q = lane >> 4;       // B-frag read map
        short* smw = sm_base + w * (16 * SROW);

        f32x4 acc[4];
#pragma unroll
        for (int ot = 0; ot < 4; ot++) acc[ot] = (f32x4){0.f, 0.f, 0.f, 0.f};

        int kstart = (w == 0) ? 0 : 13 + (w - 1) * 12;
        int kend   = (w == 0) ? 13 : kstart + 12;

        float dy = off[(2 * kstart) * HWSZ + gp_s];
        float dx = off[(2 * kstart + 1) * HWSZ + gp_s];
        float mm = msk[kstart * HWSZ + gp_s];

#pragma unroll 1
        for (int k = kstart; k < kend; k++) {
            int ky = k / 7, kx = k % 7;
            float y = (float)(gy  - 3 + ky) + dy;
            float x = (float)(sgx - 3 + kx) + dx;
            float y0f = floorf(y), x0f = floorf(x);
            float wy = y - y0f, wx = x - x0f;
            int iy0 = (int)y0f, ix0 = (int)x0f;
            int iy1 = iy0 + 1, ix1 = ix0 + 1;
            bool vy0 = (iy0 >= 0) & (iy0 < HH);
            bool vy1 = (iy1 >= 0) & (iy1 < HH);
            bool vx0 = (ix0 >= 0) & (ix0 < WW);
            bool vx1 = (ix1 >= 0) & (ix1 < WW);
            int iy0c = min(max(iy0, 0), HH - 1), iy1c = min(max(iy1, 0), HH - 1);
            int ix0c = min(max(ix0, 0), WW - 1), ix1c = min(max(ix1, 0), WW - 1);
            float a00 = (vy0 & vx0) ? (1.f - wy) * (1.f - wx) * mm : 0.f;
            float a01 = (vy0 & vx1) ? (1.f - wy) * wx * mm : 0.f;
            float a10 = (vy1 & vx0) ? wy * (1.f - wx) * mm : 0.f;
            float a11 = (vy1 & vx1) ? wy * wx * mm : 0.f;

            // f16 corners: 16 ch per lane = 2x16B per corner (quad-coalesced)
            const unsigned short* b00p = encH + (iy0c * WW + ix0c) * 64 + g * 16;
            const unsigned short* b01p = encH + (iy0c * WW + ix1c) * 64 + g * 16;
            const unsigned short* b10p = encH + (iy1c * WW + ix0c) * 64 + g * 16;
            const unsigned short* b11p = encH + (iy1c * WW + ix1c) * 64 + g * 16;
            uint4 u00[2], u01[2], u10[2], u11[2];
            u00[0] = *(const uint4*)b00p;  u00[1] = *(const uint4*)(b00p + 8);
            u01[0] = *(const uint4*)b01p;  u01[1] = *(const uint4*)(b01p + 8);
            u10[0] = *(const uint4*)b10p;  u10[1] = *(const uint4*)(b10p + 8);
            u11[0] = *(const uint4*)b11p;  u11[1] = *(const uint4*)(b11p + 8);

            // prefetch next-tap offsets
            float dyn = 0.f, dxn = 0.f, mmn = 0.f;
            if (k + 1 < kend) {
                dyn = off[(2 * k + 2) * HWSZ + gp_s];
                dxn = off[(2 * k + 3) * HWSZ + gp_s];
                mmn = msk[(k + 1) * HWSZ + gp_s];
            }

            // A-frag loads (L2-hot, independent of samples)
            h16x8 af[8];
#pragma unroll
            for (int f = 0; f < 8; f++)
                af[f] = *(const h16x8*)&wA[(k * 8 + f) * 512 + lane * 8];

            // packed-f16 blend: 4 cvt + 32 v_pk_fma_f16; output already packed
            h16x2 w00 = cvt2h(a00);
            h16x2 w01 = cvt2h(a01);
            h16x2 w10 = cvt2h(a10);
            h16x2 w11 = cvt2h(a11);

            unsigned c00[8] = {u00[0].x, u00[0].y, u00[0].z, u00[0].w,
                               u00[1].x, u00[1].y, u00[1].z, u00[1].w};
            unsigned c01[8] = {u01[0].x, u01[0].y, u01[0].z, u01[0].w,
                               u01[1].x, u01[1].y, u01[1].z, u01[1].w};
            unsigned c10[8] = {u10[0].x, u10[0].y, u10[0].z, u10[0].w,
                               u10[1].x, u10[1].y, u10[1].z, u10[1].w};
            unsigned c11[8] = {u11[0].x, u11[0].y, u11[0].z, u11[0].w,
                               u11[1].x, u11[1].y, u11[1].z, u11[1].w};
            unsigned pk[8];
#pragma unroll
            for (int j = 0; j < 8; j++) {
                h16x2 r = as_h2(c00[j]) * w00;
                r = as_h2(c01[j]) * w01 + r;
                r = as_h2(c10[j]) * w10 + r;
                r = as_h2(c11[j]) * w11 + r;
                pk[j] = as_u(r);
            }
            *(uint4*)&smw[sp * SROW + g * 16]     = make_uint4(pk[0], pk[1], pk[2], pk[3]);
            *(uint4*)&smw[sp * SROW + g * 16 + 8] = make_uint4(pk[4], pk[5], pk[6], pk[7]);

            h16x8 b0 = *(const h16x8*)&smw[n * SROW +  0 + q * 8];
            h16x8 b1 = *(const h16x8*)&smw[n * SROW + 32 + q * 8];

#pragma unroll
            for (int ot = 0; ot < 4; ot++) {
                acc[ot] = __builtin_amdgcn_mfma_f32_16x16x32_f16(af[ot * 2],     b0, acc[ot], 0, 0, 0);
                acc[ot] = __builtin_amdgcn_mfma_f32_16x16x32_f16(af[ot * 2 + 1], b1, acc[ot], 0, 0, 0);
            }

            dy = dyn; dx = dxn; mm = mmn;
        }

        // two-phase tree reduction (2-slot buffer)
        if (w >= 2) {
            float* rp = &red[((w - 2) * 64 + lane) * REDW];
#pragma unroll
            for (int ot = 0; ot < 4; ot++)
                *(float4*)&rp[ot * 4] = make_float4(acc[ot][0], acc[ot][1], acc[ot][2], acc[ot][3]);
        }
        __syncthreads();
        if (w < 2) {
            const float* rp = &red[(w * 64 + lane) * REDW];
#pragma unroll
            for (int ot = 0; ot < 4; ot++) {
                float4 v = *(const float4*)&rp[ot * 4];
                acc[ot][0] += v.x; acc[ot][1] += v.y;
                acc[ot][2] += v.z; acc[ot][3] += v.w;
            }
        }
        __syncthreads();
        if (w == 1) {
            float* rp = &red[lane * REDW];
#pragma unroll
            for (int ot = 0; ot < 4; ot++)
                *(float4*)&rp[ot * 4] = make_float4(acc[ot][0], acc[ot][1], acc[ot][2], acc[ot][3]);
        }
        __syncthreads();
        if (w == 0) {
            const float* rp = &red[lane * REDW];
#pragma unroll
            for (int ot = 0; ot < 4; ot++) {
                float4 v = *(const float4*)&rp[ot * 4];
                acc[ot][0] += v.x; acc[ot][1] += v.y;
                acc[ot][2] += v.z; acc[ot][3] += v.w;
            }
            int gp_m = gy * WW + gx0 + n;
            // f16 rev: lane holds ch ot*16+q*4..+3 of pixel gp_m
#pragma unroll
            for (int ot = 0; ot < 4; ot++) {
                unsigned u0 = pkh(acc[ot][0], acc[ot][1]);
                unsigned u1 = pkh(acc[ot][2], acc[ot][3]);
                *(uint2*)&revH[gp_m * 64 + ot * 16 + q * 4] = make_uint2(u0, u1);
            }
        }
        return;
    }

    // ================= fft =================
    {
        short* sbf = (short*)smem_raw;                 // 9216 B
        short* e0H = (short*)(smem_raw + 64 * SROW * 2); // 9216 B

        int pb = b - 2304;
        int pbx = pb % 24, pby = pb / 24;
        int gx0 = pbx * 8, gy0 = pby * 8;

#pragma unroll
        for (int r = 0; r < 2; r++) {
            int idx = t + r * 256;             // 512 x 8-ch units
            int px = idx >> 3, g8 = idx & 7;
            int gy = gy0 + (px >> 3), gx = gx0 + (px & 7);
            *(uint4*)&sbf[px * SROW + g8 * 8] =
                *(const uint4*)&encH[(gy * WW + gx) * 64 + g8 * 8];
        }
        __syncthreads();

        int n = lane & 15, q = lane >> 4;
        h16x8 a0 = *(const h16x8*)&wpiA[(w * 2 + 0) * 512 + lane * 8];
        h16x8 a1 = *(const h16x8*)&wpiA[(w * 2 + 1) * 512 + lane * 8];
#pragma unroll
        for (int j = 0; j < 4; j++) {
            h16x8 b0 = *(const h16x8*)&sbf[(j * 16 + n) * SROW +  0 + q * 8];
            h16x8 b1 = *(const h16x8*)&sbf[(j * 16 + n) * SROW + 32 + q * 8];
            f32x4 acc = {0.f, 0.f, 0.f, 0.f};
            acc = __builtin_amdgcn_mfma_f32_16x16x32_f16(a0, b0, acc, 0, 0, 0);
            acc = __builtin_amdgcn_mfma_f32_16x16x32_f16(a1, b1, acc, 0, 0, 0);
            // f16 e0: lane writes ch w*16+q*4..+3 of px j*16+n
            unsigned u0 = pkh(acc[0], acc[1]);
            unsigned u1 = pkh(acc[2], acc[3]);
            *(unsigned*)&e0H[(j * 16 + n) * SROW + w * 16 + q * 4]     = u0;
            *(unsigned*)&e0H[(j * 16 + n) * SROW + w * 16 + q * 4 + 2] = u1;
        }
        __syncthreads();

        int o = t & 63;
        int yb = t >> 6;
#pragma unroll
        for (int yy = 0; yy < 2; yy++) {
            int y = yb + yy * 4;
            float outr[8];
#pragma unroll
            for (int x = 0; x < 8; x++) outr[x] = 0.f;
#pragma unroll
            for (int u = 0; u < 8; u++) {
                int ry = (y - u + 8) & 7;
                float row[8];
#pragma unroll
                for (int rx = 0; rx < 8; rx++)
                    row[rx] = h2f(((const unsigned short*)e0H)[(ry * 8 + rx) * SROW + o]);
#pragma unroll
                for (int v = 0; v < 8; v++) {
                    float kv = krT[(u * 8 + v) * 64 + o];
#pragma unroll
                    for (int x = 0; x < 8; x++)
                        outr[x] += kv * row[(x - v + 8) & 7];
                }
            }
            int gy = gy0 + y;
#pragma unroll
            for (int x = 0; x < 8; x++)
                e1H[(gy * WW + gx0 + x) * 64 + o] = f2h(outr[x]);
        }
    }
}

// ---------------------------------------------------------------------------
// k_c3out R20: fused conv3x3(e1+rev, f16) -> [.,dec] -> proj_out -> SimpleGate
// with FULLY-COALESCED dec reads and out writes:
//  - dec staged block-wide (256B full-line loads, 64 consecutive px) into
//    decS[cp][px] f16-pairs; proj_out kt>=2 B-frags read 4x ds_read_b32.
//  - out staged to outS[c][px] (reusing dead sm region) then written 256B
//    coalesced per channel plane.
// Replaces the 64B quarter-line segment pattern (4x request inflation) on
// 38 MB of fp32 traffic. Numerically identical to R16.
// ---------------------------------------------------------------------------
__global__ __launch_bounds__(256) void k_c3out(
    const unsigned short* __restrict__ e1H, const unsigned short* __restrict__ revH,
    const short* __restrict__ w2A, const float* __restrict__ dec,
    const short* __restrict__ wpoA, float* __restrict__ out)
{
    __shared__ __align__(16) short sm[4][54 * C3ROW];  // 31104 B (per-wave stage)
    __shared__ __align__(16) unsigned decS[32 * 66];   //  8448 B (block-wide dec)
    int t = threadIdx.x;
    int lane = t & 63, w = t >> 6;
    int b = blockIdx.x;
    int xcd = b & 7, blk = b >> 3;
    int gy  = xcd * 24 + blk / 3;
    int gxb = (blk % 3) * 64;              // block px base
    int gx0 = gxb + w * 16;                // wave px base
    short* smw = &sm[w][0];
    int n = lane & 15, q = lane >> 4;
    int gpb = gy * WW + gxb;

    // ---- block-wide dec stage: full-line coalesced (64 px x 256B / plane) ----
    {
        int px = t & 63, cq = t >> 6;      // cq = w
#pragma unroll
        for (int r = 0; r < 8; r++) {
            int cp = cq + 4 * r;           // ch-pair 0..31
            int c0 = cp * 2;
            float v0 = dec[c0 * HWSZ + gpb + px];
            float v1 = dec[(c0 + 1) * HWSZ + gpb + px];
            decS[cp * 66 + px] = pkh(v0, v1);
        }
    }

    // ---- per-wave e1+rev halo stage (unchanged) ----
    for (int r = 0; r < 14; r++) {
        int u = lane + r * 64;
        if (u < 864) {
            int rp = u >> 4, g = u & 15;
            int row = rp / 18, pxl = rp - row * 18;
            int gyy = gy + row - 1, gxx = gx0 + pxl - 1;
            uint2 v = make_uint2(0u, 0u);
            if (gyy >= 0 && gyy < HH && gxx >= 0 && gxx < WW) {
                int gp = (gyy * WW + gxx) * 64 + g * 4;    // short index
                uint2 va = *(const uint2*)&e1H[gp];
                uint2 vb = *(const uint2*)&revH[gp];
                v.x = as_u(as_h2(va.x) + as_h2(vb.x));
                v.y = as_u(as_h2(va.y) + as_h2(vb.y));
            }
            *(uint2*)&smw[rp * C3ROW + g * 4] = v;
        }
    }
    __syncthreads();    // decS visible to all waves (smw is per-wave anyway)

    f32x4 acc[4];
#pragma unroll
    for (int ot = 0; ot < 4; ot++) acc[ot] = (f32x4){0.f, 0.f, 0.f, 0.f};

#pragma unroll 1
    for (int tap = 0; tap < 9; tap++) {
        int dy = tap / 3, dx = tap - dy * 3;
        int rp = dy * 18 + n + dx;
        h16x8 b0 = *(const h16x8*)&smw[rp * C3ROW +  0 + q * 8];
        h16x8 b1 = *(const h16x8*)&smw[rp * C3ROW + 32 + q * 8];
#pragma unroll
        for (int ot = 0; ot < 4; ot++) {
            h16x8 a0 = *(const h16x8*)&w2A[(tap * 8 + ot * 2 + 0) * 512 + lane * 8];
            h16x8 a1 = *(const h16x8*)&w2A[(tap * 8 + ot * 2 + 1) * 512 + lane * 8];
            acc[ot] = __builtin_amdgcn_mfma_f32_16x16x32_f16(a0, b0, acc[ot], 0, 0, 0);
            acc[ot] = __builtin_amdgcn_mfma_f32_16x16x32_f16(a1, b1, acc[ot], 0, 0, 0);
        }
    }

    // e3 (C-layout regs) -> B-frag rows in smw (shorts 0..63 per px)
#pragma unroll
    for (int ot = 0; ot < 4; ot++) {
        unsigned lo = pkh(acc[ot][0], acc[ot][1]);
        unsigned hi = pkh(acc[ot][2], acc[ot][3]);
        *(uint2*)&smw[n * OROW + ot * 16 + q * 4] = make_uint2(lo, hi);
    }

    f32x4 go[8];
#pragma unroll
    for (int ot = 0; ot < 8; ot++) go[ot] = (f32x4){0.f, 0.f, 0.f, 0.f};

#pragma unroll 1
    for (int kt = 0; kt < 4; kt++) {
        h16x8 bb;
        if (kt < 2) {
            bb = *(const h16x8*)&smw[n * OROW + kt * 32 + q * 8];
        } else {
            union { unsigned u[4]; h16x8 v; } tmp;
            int px = w * 16 + n;
            int cp0 = (kt - 2) * 16 + q * 4;
            tmp.u[0] = decS[(cp0 + 0) * 66 + px];
            tmp.u[1] = decS[(cp0 + 1) * 66 + px];
            tmp.u[2] = decS[(cp0 + 2) * 66 + px];
            tmp.u[3] = decS[(cp0 + 3) * 66 + px];
            bb = tmp.v;
        }
#pragma unroll
        for (int ot = 0; ot < 8; ot++) {
            h16x8 aa = *(const h16x8*)&wpoA[(ot * 4 + kt) * 512 + lane * 8];
            go[ot] = __builtin_amdgcn_mfma_f32_16x16x32_f16(aa, bb, go[ot], 0, 0, 0);
        }
    }

    // ---- SimpleGate -> outS[c][px] (reuse dead sm region) -> coalesced out ----
    __syncthreads();                       // all waves done reading smw
    float* outS = (float*)&sm[0][0];       // 64*66*4 = 16896 B <= 31104 B
#pragma unroll
    for (int ot = 0; ot < 4; ot++)
#pragma unroll
        for (int r = 0; r < 4; r++)
            outS[(ot * 16 + q * 4 + r) * 66 + w * 16 + n] = go[ot][r] * go[ot + 4][r];
    __syncthreads();
    {
        int px = t & 63;
#pragma unroll
        for (int r2 = 0; r2 < 16; r2++) {
            int c = (t >> 6) + 4 * r2;
            out[c * HWSZ + gpb + px] = outS[c * 66 + px];
        }
    }
}

// ---------------------------------------------------------------------------
extern "C" void kernel_launch(void* const* d_in, const int* in_sizes, int n_in,
                              void* d_out, int out_size, void* d_ws, size_t ws_size,
                              hipStream_t stream)
{
    const float* enc  = (const float*)d_in[0];
    const float* dec  = (const float*)d_in[1];
    const float* ioff = (const float*)d_in[2];
    const float* iwt  = (const float*)d_in[3];
    const float* wpi  = (const float*)d_in[4];
    const float* fw   = (const float*)d_in[5];
    const float* wpo  = (const float*)d_in[6];
    const float* wd   = (const float*)d_in[7];
    const float* wc1  = (const float*)d_in[8];
    const float* wc2  = (const float*)d_in[9];
    float* out = (float*)d_out;
    float* ws  = (float*)d_ws;

    float*          krT  = ws;                               //   4096 fl
    unsigned short* revH = (unsigned short*)(ws + 4096);     // 2359296 sh
    unsigned short* e1H  = (unsigned short*)(ws + 1183744);  // 2359296 sh
    unsigned short* encH = (unsigned short*)(ws + 2363392);  // 2359296 sh
    short*          wA   = (short*)(ws + 3543040);           // 200704 sh
    short*          w2A  = (short*)(ws + 3643392);           //  36864 sh
    short*          wpoA = (short*)(ws + 3661824);           //  16384 sh
    short*          wpiA = (short*)(ws + 3670016);           //   4096 sh

    hipLaunchKernelGGL(k_pt,    dim3(625),  dim3(256), 0, stream,
                       enc, encH, fw, wd, wc2, wc1, wpo, wpi, krT, wA, w2A, wpoA, wpiA);
    hipLaunchKernelGGL(k_dff,   dim3(2880), dim3(256), 0, stream,
                       encH, ioff, iwt, wA, revH, wpiA, krT, e1H);
    hipLaunchKernelGGL(k_c3out, dim3(576),  dim3(256), 0, stream,
                       e1H, revH, w2A, dec, wpoA, out);
}

// Round 15
// 187.287 us; speedup vs baseline: 3.1981x; 1.0013x over previous
//
#include <hip/hip_runtime.h>
#include <math.h>

#define CH    64
#define WW    192
#define HH    192
#define HWSZ  (192*192)
#define KK    49
#define ROWP  68   // padded fp32 LDS row (dwords)
#define SROW  72   // f16 row stride in shorts (144B)
#define C3ROW 72   // conv3 staged px stride (shorts)
#define OROW  136  // k_out staged px stride (shorts)
#define REDW  20   // reduction row stride (floats): 80B, 16B-aligned

typedef __attribute__((ext_vector_type(8))) short     s16x8;
typedef __attribute__((ext_vector_type(8))) _Float16  h16x8;  // 8 f16 = 4 VGPR
typedef __attribute__((ext_vector_type(2))) _Float16  h16x2;
typedef __attribute__((ext_vector_type(2))) __fp16    fp16x2; // cvt_pkrtz result type
typedef __attribute__((ext_vector_type(4))) float     f32x4;

__device__ __forceinline__ unsigned short f2h(float f) {
    union { _Float16 h; unsigned short s; } u; u.h = (_Float16)f;  // RNE
    return u.s;
}

__device__ __forceinline__ float h2f(unsigned short s) {
    union { unsigned short s; _Float16 h; } u; u.s = s;
    return (float)u.h;
}

// pack two floats to f16x2 (RTZ, single v_cvt_pkrtz_f16_f32)
__device__ __forceinline__ unsigned pkh(float lo, float hi) {
    union { fp16x2 h; unsigned u; } v;
    v.h = __builtin_amdgcn_cvt_pkrtz(lo, hi);
    return v.u;
}

// broadcast one float into packed f16x2 (for pk_fma weights)
__device__ __forceinline__ h16x2 cvt2h(float a) {
    union { fp16x2 h; h16x2 o; } v;
    v.h = __builtin_amdgcn_cvt_pkrtz(a, a);
    return v.o;
}

__device__ __forceinline__ h16x2 as_h2(unsigned u) {
    union { unsigned u; h16x2 h; } v; v.u = u; return v.h;
}

__device__ __forceinline__ unsigned as_u(h16x2 h) {
    union { h16x2 h; unsigned u; } v; v.h = h; return v.u;
}

// ---------------------------------------------------------------------------
// k_pt (grid 625): b<576 -> trans (enc fp32 [c][p] -> encH f16 [p][c]);
// b>=576 -> prep tap k=b-576 (krT + A-frag packs).
// ---------------------------------------------------------------------------
__device__ const float c_cos8[8] = {
    1.f, 0.70710678118654752f, 0.f, -0.70710678118654752f,
   -1.f, -0.70710678118654752f, 0.f, 0.70710678118654752f };

__global__ __launch_bounds__(256) void k_pt(
    const float* __restrict__ enc,  // trans input
    unsigned short* __restrict__ encH,
    const float* __restrict__ fw,   // [64,1,1,8,5]
    const float* __restrict__ wd,   // [64,64,7,7]
    const float* __restrict__ w2,   // [64,64,3,3]
    const float* __restrict__ wc1,  // [64,64,1,1]
    const float* __restrict__ wpo,  // [128,128]
    const float* __restrict__ wpi,  // [64,64]
    float* __restrict__ krT,        // [64 uv][64 c]
    short* __restrict__ wA,         // [49*8*512]
    short* __restrict__ w2A,        // [9*8*512]
    short* __restrict__ wpoA,       // [32*512]
    short* __restrict__ wpiA)       // [8*512]
{
    __shared__ __align__(16) char smem_raw[2 * 64 * ROWP * 4];  // 34816 B
    int b = blockIdx.x;
    int t = threadIdx.x;

    if (b < 576) {
        // ---- trans ----
        float* s = (float*)smem_raw;           // 64*65 floats = 16640 B
        int base = b * 64;
#pragma unroll
        for (int r = 0; r < 16; r++) {
            int idx = t + r * 256;
            int p = idx & 63, c = idx >> 6;
            s[p * 65 + c] = enc[c * HWSZ + base + p];
        }
        __syncthreads();
#pragma unroll
        for (int r = 0; r < 8; r++) {
            int idx = t + r * 256;             // 2048 pair-units
            int pr = idx & 31, p = idx >> 5;   // pair 0..31, px 0..63
            ((unsigned*)encH)[(base + p) * 32 + pr] =
                pkh(s[p * 65 + 2 * pr], s[p * 65 + 2 * pr + 1]);
        }
        return;
    }

    // ---- prep ----
    int kb = b - 576;                          // 0..48
    int tid = kb * 256 + t;
    int nt  = 49 * 256;
    for (int u = tid; u < 64 * 64; u += nt) {
        int uv = u >> 6, c = u & 63;
        int uu = uv >> 3, v = uv & 7;
        float acc = 0.f;
        for (int ky = 0; ky < 8; ky++)
            for (int kx = 0; kx < 8; kx++) {
                float wv = (kx <= 4) ? fw[c * 40 + ky * 5 + kx]
                                     : fw[c * 40 + ((8 - ky) & 7) * 5 + (8 - kx)];
                acc += wv * c_cos8[(ky * uu + kx * v) & 7];
            }
        krT[uv * 64 + c] = acc * (1.f / 64.f);
    }
    for (int u = tid; u < 9 * 4096; u += nt) {
        int tap = u / 4096, rem = u & 4095;
        int o = rem >> 6, c = rem & 63;
        float v = w2[(o * 64 + c) * 9 + tap];
        int fi = tap * 8 + (o >> 4) * 2 + (c >> 5);
        int ln = ((c >> 3) & 3) * 16 + (o & 15);
        w2A[fi * 512 + ln * 8 + (c & 7)] = (short)f2h(v);
    }
    for (int u = tid; u < 128 * 128; u += nt) {
        int o = u >> 7, c = u & 127;
        int fi = (o >> 4) * 4 + (c >> 5);
        int ln = ((c >> 3) & 3) * 16 + (o & 15);
        wpoA[fi * 512 + ln * 8 + (c & 7)] = (short)f2h(wpo[u]);
    }
    for (int u = tid; u < 64 * 64; u += nt) {
        int o = u >> 6, c = u & 63;
        int fi = (o >> 4) * 2 + (c >> 5);
        int ln = ((c >> 3) & 3) * 16 + (o & 15);
        wpiA[fi * 512 + ln * 8 + (c & 7)] = (short)f2h(wpi[u]);
    }

    // ---- fold wc1 @ wd + pack: one block per tap kb ----
    float* wdk  = (float*)smem_raw;            // 64*ROWP floats
    float* wc1s = wdk + 64 * ROWP;             // 64*ROWP floats
#pragma unroll
    for (int r = 0; r < 16; r++) {
        int idx = t + r * 256;
        int o = idx >> 6, c = idx & 63;
        wdk [o * ROWP + c] = wd[(o * 64 + c) * KK + kb];
        wc1s[o * ROWP + c] = wc1[o * 64 + c];
    }
    __syncthreads();

    int ot = (t >> 4) * 4, cb = (t & 15) * 4;
    float a[4][4];
#pragma unroll
    for (int i = 0; i < 4; i++)
#pragma unroll
        for (int j = 0; j < 4; j++) a[i][j] = 0.f;
    for (int o = 0; o < 64; o++) {
        float wv_[4], sv_[4];
#pragma unroll
        for (int i = 0; i < 4; i++) wv_[i] = wc1s[(ot + i) * ROWP + o];
#pragma unroll
        for (int j = 0; j < 4; j++) sv_[j] = wdk[o * ROWP + cb + j];
#pragma unroll
        for (int i = 0; i < 4; i++)
#pragma unroll
            for (int j = 0; j < 4; j++) a[i][j] += wv_[i] * sv_[j];
    }
#pragma unroll
    for (int i = 0; i < 4; i++)
#pragma unroll
        for (int j = 0; j < 4; j++) {
            int o2 = ot + i, c = cb + j;
            int tt = o2 >> 4, m = o2 & 15;
            int kt = c >> 5, q2 = (c >> 3) & 3, jj = c & 7;
            int ln = q2 * 16 + m;
            wA[(kb * 8 + tt * 2 + kt) * 512 + ln * 8 + jj] = (short)f2h(a[i][j]);
        }
}

// ---------------------------------------------------------------------------
// k_dff R21 (grid 1728): b<1152 -> deform DUAL-STRIP (two adjacent 16-px
// strips per block; af[8] loaded ONCE per tap and reused for both strips ->
// A-frag L2 traffic halves, 1.8GB->1.35GB total); b>=1152 -> fft.
// Strip-sequential gathers bound VGPR (R15 lesson: ILP bought with occupancy
// loses). rev and e1 written f16 [px][64].
// ---------------------------------------------------------------------------
__global__ __launch_bounds__(256) void k_dff(
    const unsigned short* __restrict__ encH, const float* __restrict__ off,
    const float* __restrict__ msk, const short* __restrict__ wA,
    unsigned short* __restrict__ revH,
    const short* __restrict__ wpiA, const float* __restrict__ krT,
    unsigned short* __restrict__ e1H)
{
    __shared__ __align__(16) char smem_raw[28672];
    int t = threadIdx.x;
    int lane = t & 63, w = t >> 6;
    int b = blockIdx.x;

    if (b < 1152) {
        // ================= deform (dual-strip) =================
        short* sm_base = (short*)smem_raw;                   // 4 x 32*SROW shorts = 18432
        float* red = (float*)(smem_raw + 4 * 32 * SROW * 2); // 2*64*REDW floats = 10240

        int xcd = b & 7, blk = b >> 3;          // 144 strip-pairs per xcd band
        int gy  = xcd * 24 + blk / 6;
        int gx0 = (blk % 6) * 32;               // strip A at gx0, strip B at gx0+16

        int sp = lane >> 2, g = lane & 3;       // gather map: quad-coalesced
        int sgxA = gx0 + sp,       sgxB = gx0 + 16 + sp;
        int gpA  = gy * WW + sgxA, gpB  = gy * WW + sgxB;
        int n = lane & 15, q = lane >> 4;       // B-frag read map
        short* smw = sm_base + w * (32 * SROW);

        f32x4 accA[4], accB[4];
#pragma unroll
        for (int ot = 0; ot < 4; ot++) {
            accA[ot] = (f32x4){0.f, 0.f, 0.f, 0.f};
            accB[ot] = (f32x4){0.f, 0.f, 0.f, 0.f};
        }

        int kstart = (w == 0) ? 0 : 13 + (w - 1) * 12;
        int kend   = (w == 0) ? 13 : kstart + 12;

        float dyA = off[(2 * kstart) * HWSZ + gpA];
        float dxA = off[(2 * kstart + 1) * HWSZ + gpA];
        float mmA = msk[kstart * HWSZ + gpA];
        float dyB = off[(2 * kstart) * HWSZ + gpB];
        float dxB = off[(2 * kstart + 1) * HWSZ + gpB];
        float mmB = msk[kstart * HWSZ + gpB];

#pragma unroll 1
        for (int k = kstart; k < kend; k++) {
            int ky = k / 7, kx = k % 7;

            // ---- strip A setup + gather ----
            float yA = (float)(gy - 3 + ky) + dyA;
            float xA = (float)(sgxA - 3 + kx) + dxA;
            float y0fA = floorf(yA), x0fA = floorf(xA);
            float wyA = yA - y0fA, wxA = xA - x0fA;
            int iy0A = (int)y0fA, ix0A = (int)x0fA;
            int iy1A = iy0A + 1, ix1A = ix0A + 1;
            bool vy0A = (iy0A >= 0) & (iy0A < HH);
            bool vy1A = (iy1A >= 0) & (iy1A < HH);
            bool vx0A = (ix0A >= 0) & (ix0A < WW);
            bool vx1A = (ix1A >= 0) & (ix1A < WW);
            int iy0cA = min(max(iy0A, 0), HH - 1), iy1cA = min(max(iy1A, 0), HH - 1);
            int ix0cA = min(max(ix0A, 0), WW - 1), ix1cA = min(max(ix1A, 0), WW - 1);
            float a00A = (vy0A & vx0A) ? (1.f - wyA) * (1.f - wxA) * mmA : 0.f;
            float a01A = (vy0A & vx1A) ? (1.f - wyA) * wxA * mmA : 0.f;
            float a10A = (vy1A & vx0A) ? wyA * (1.f - wxA) * mmA : 0.f;
            float a11A = (vy1A & vx1A) ? wyA * wxA * mmA : 0.f;

            const unsigned short* pA00 = encH + (iy0cA * WW + ix0cA) * 64 + g * 16;
            const unsigned short* pA01 = encH + (iy0cA * WW + ix1cA) * 64 + g * 16;
            const unsigned short* pA10 = encH + (iy1cA * WW + ix0cA) * 64 + g * 16;
            const unsigned short* pA11 = encH + (iy1cA * WW + ix1cA) * 64 + g * 16;
            uint4 uA00[2], uA01[2], uA10[2], uA11[2];
            uA00[0] = *(const uint4*)pA00;  uA00[1] = *(const uint4*)(pA00 + 8);
            uA01[0] = *(const uint4*)pA01;  uA01[1] = *(const uint4*)(pA01 + 8);
            uA10[0] = *(const uint4*)pA10;  uA10[1] = *(const uint4*)(pA10 + 8);
            uA11[0] = *(const uint4*)pA11;  uA11[1] = *(const uint4*)(pA11 + 8);

            // ---- A-frags: ONE load per tap, shared by both strips ----
            h16x8 af[8];
#pragma unroll
            for (int f = 0; f < 8; f++)
                af[f] = *(const h16x8*)&wA[(k * 8 + f) * 512 + lane * 8];

            // ---- strip A blend + bounce + MFMA ----
            {
                h16x2 w00 = cvt2h(a00A), w01 = cvt2h(a01A);
                h16x2 w10 = cvt2h(a10A), w11 = cvt2h(a11A);
                unsigned c00[8] = {uA00[0].x, uA00[0].y, uA00[0].z, uA00[0].w,
                                   uA00[1].x, uA00[1].y, uA00[1].z, uA00[1].w};
                unsigned c01[8] = {uA01[0].x, uA01[0].y, uA01[0].z, uA01[0].w,
                                   uA01[1].x, uA01[1].y, uA01[1].z, uA01[1].w};
                unsigned c10[8] = {uA10[0].x, uA10[0].y, uA10[0].z, uA10[0].w,
                                   uA10[1].x, uA10[1].y, uA10[1].z, uA10[1].w};
                unsigned c11[8] = {uA11[0].x, uA11[0].y, uA11[0].z, uA11[0].w,
                                   uA11[1].x, uA11[1].y, uA11[1].z, uA11[1].w};
                unsigned pk[8];
#pragma unroll
                for (int j = 0; j < 8; j++) {
                    h16x2 r = as_h2(c00[j]) * w00;
                    r = as_h2(c01[j]) * w01 + r;
                    r = as_h2(c10[j]) * w10 + r;
                    r = as_h2(c11[j]) * w11 + r;
                    pk[j] = as_u(r);
                }
                *(uint4*)&smw[sp * SROW + g * 16]     = make_uint4(pk[0], pk[1], pk[2], pk[3]);
                *(uint4*)&smw[sp * SROW + g * 16 + 8] = make_uint4(pk[4], pk[5], pk[6], pk[7]);

                h16x8 b0 = *(const h16x8*)&smw[n * SROW +  0 + q * 8];
                h16x8 b1 = *(const h16x8*)&smw[n * SROW + 32 + q * 8];
#pragma unroll
                for (int ot = 0; ot < 4; ot++) {
                    accA[ot] = __builtin_amdgcn_mfma_f32_16x16x32_f16(af[ot * 2],     b0, accA[ot], 0, 0, 0);
                    accA[ot] = __builtin_amdgcn_mfma_f32_16x16x32_f16(af[ot * 2 + 1], b1, accA[ot], 0, 0, 0);
                }
            }

            // ---- strip B setup + gather (after A consumed: bounded VGPR) ----
            float yB = (float)(gy - 3 + ky) + dyB;
            float xB = (float)(sgxB - 3 + kx) + dxB;
            float y0fB = floorf(yB), x0fB = floorf(xB);
            float wyB = yB - y0fB, wxB = xB - x0fB;
            int iy0B = (int)y0fB, ix0B = (int)x0fB;
            int iy1B = iy0B + 1, ix1B = ix0B + 1;
            bool vy0B = (iy0B >= 0) & (iy0B < HH);
            bool vy1B = (iy1B >= 0) & (iy1B < HH);
            bool vx0B = (ix0B >= 0) & (ix0B < WW);
            bool vx1B = (ix1B >= 0) & (ix1B < WW);
            int iy0cB = min(max(iy0B, 0), HH - 1), iy1cB = min(max(iy1B, 0), HH - 1);
            int ix0cB = min(max(ix0B, 0), WW - 1), ix1cB = min(max(ix1B, 0), WW - 1);
            float a00B = (vy0B & vx0B) ? (1.f - wyB) * (1.f - wxB) * mmB : 0.f;
            float a01B = (vy0B & vx1B) ? (1.f - wyB) * wxB * mmB : 0.f;
            float a10B = (vy1B & vx0B) ? wyB * (1.f - wxB) * mmB : 0.f;
            float a11B = (vy1B & vx1B) ? wyB * wxB * mmB : 0.f;

            const unsigned short* pB00 = encH + (iy0cB * WW + ix0cB) * 64 + g * 16;
            const unsigned short* pB01 = encH + (iy0cB * WW + ix1cB) * 64 + g * 16;
            const unsigned short* pB10 = encH + (iy1cB * WW + ix0cB) * 64 + g * 16;
            const unsigned short* pB11 = encH + (iy1cB * WW + ix1cB) * 64 + g * 16;
            uint4 uB00[2], uB01[2], uB10[2], uB11[2];
            uB00[0] = *(const uint4*)pB00;  uB00[1] = *(const uint4*)(pB00 + 8);
            uB01[0] = *(const uint4*)pB01;  uB01[1] = *(const uint4*)(pB01 + 8);
            uB10[0] = *(const uint4*)pB10;  uB10[1] = *(const uint4*)(pB10 + 8);
            uB11[0] = *(const uint4*)pB11;  uB11[1] = *(const uint4*)(pB11 + 8);

            // prefetch next-tap offsets (both strips)
            if (k + 1 < kend) {
                dyA = off[(2 * k + 2) * HWSZ + gpA];
                dxA = off[(2 * k + 3) * HWSZ + gpA];
                mmA = msk[(k + 1) * HWSZ + gpA];
                dyB = off[(2 * k + 2) * HWSZ + gpB];
                dxB = off[(2 * k + 3) * HWSZ + gpB];
                mmB = msk[(k + 1) * HWSZ + gpB];
            }

            // ---- strip B blend + bounce + MFMA (rows 16+) ----
            {
                h16x2 w00 = cvt2h(a00B), w01 = cvt2h(a01B);
                h16x2 w10 = cvt2h(a10B), w11 = cvt2h(a11B);
                unsigned c00[8] = {uB00[0].x, uB00[0].y, uB00[0].z, uB00[0].w,
                                   uB00[1].x, uB00[1].y, uB00[1].z, uB00[1].w};
                unsigned c01[8] = {uB01[0].x, uB01[0].y, uB01[0].z, uB01[0].w,
                                   uB01[1].x, uB01[1].y, uB01[1].z, uB01[1].w};
                unsigned c10[8] = {uB10[0].x, uB10[0].y, uB10[0].z, uB10[0].w,
                                   uB10[1].x, uB10[1].y, uB10[1].z, uB10[1].w};
                unsigned c11[8] = {uB11[0].x, uB11[0].y, uB11[0].z, uB11[0].w,
                                   uB11[1].x, uB11[1].y, uB11[1].z, uB11[1].w};
                unsigned pk[8];
#pragma unroll
                for (int j = 0; j < 8; j++) {
                    h16x2 r = as_h2(c00[j]) * w00;
                    r = as_h2(c01[j]) * w01 + r;
                    r = as_h2(c10[j]) * w10 + r;
                    r = as_h2(c11[j]) * w11 + r;
                    pk[j] = as_u(r);
                }
                *(uint4*)&smw[(16 + sp) * SROW + g * 16]     = make_uint4(pk[0], pk[1], pk[2], pk[3]);
                *(uint4*)&smw[(16 + sp) * SROW + g * 16 + 8] = make_uint4(pk[4], pk[5], pk[6], pk[7]);

                h16x8 b0 = *(const h16x8*)&smw[(16 + n) * SROW +  0 + q * 8];
                h16x8 b1 = *(const h16x8*)&smw[(16 + n) * SROW + 32 + q * 8];
#pragma unroll
                for (int ot = 0; ot < 4; ot++) {
                    accB[ot] = __builtin_amdgcn_mfma_f32_16x16x32_f16(af[ot * 2],     b0, accB[ot], 0, 0, 0);
                    accB[ot] = __builtin_amdgcn_mfma_f32_16x16x32_f16(af[ot * 2 + 1], b1, accB[ot], 0, 0, 0);
                }
            }
        }

        // ---- strip A reduction + write ----
        if (w >= 2) {
            float* rp = &red[((w - 2) * 64 + lane) * REDW];
#pragma unroll
            for (int ot = 0; ot < 4; ot++)
                *(float4*)&rp[ot * 4] = make_float4(accA[ot][0], accA[ot][1], accA[ot][2], accA[ot][3]);
        }
        __syncthreads();
        if (w < 2) {
            const float* rp = &red[(w * 64 + lane) * REDW];
#pragma unroll
            for (int ot = 0; ot < 4; ot++) {
                float4 v = *(const float4*)&rp[ot * 4];
                accA[ot][0] += v.x; accA[ot][1] += v.y;
                accA[ot][2] += v.z; accA[ot][3] += v.w;
            }
        }
        __syncthreads();
        if (w == 1) {
            float* rp = &red[lane * REDW];
#pragma unroll
            for (int ot = 0; ot < 4; ot++)
                *(float4*)&rp[ot * 4] = make_float4(accA[ot][0], accA[ot][1], accA[ot][2], accA[ot][3]);
        }
        __syncthreads();
        if (w == 0) {
            const float* rp = &red[lane * REDW];
#pragma unroll
            for (int ot = 0; ot < 4; ot++) {
                float4 v = *(const float4*)&rp[ot * 4];
                accA[ot][0] += v.x; accA[ot][1] += v.y;
                accA[ot][2] += v.z; accA[ot][3] += v.w;
            }
            int gp_m = gy * WW + gx0 + n;
#pragma unroll
            for (int ot = 0; ot < 4; ot++) {
                unsigned u0 = pkh(accA[ot][0], accA[ot][1]);
                unsigned u1 = pkh(accA[ot][2], accA[ot][3]);
                *(uint2*)&revH[gp_m * 64 + ot * 16 + q * 4] = make_uint2(u0, u1);
            }
        }
        __syncthreads();

        // ---- strip B reduction + write ----
        if (w >= 2) {
            float* rp = &red[((w - 2) * 64 + lane) * REDW];
#pragma unroll
            for (int ot = 0; ot < 4; ot++)
                *(float4*)&rp[ot * 4] = make_float4(accB[ot][0], accB[ot][1], accB[ot][2], accB[ot][3]);
        }
        __syncthreads();
        if (w < 2) {
            const float* rp = &red[(w * 64 + lane) * REDW];
#pragma unroll
            for (int ot = 0; ot < 4; ot++) {
                float4 v = *(const float4*)&rp[ot * 4];
                accB[ot][0] += v.x; accB[ot][1] += v.y;
                accB[ot][2] += v.z; accB[ot][3] += v.w;
            }
        }
        __syncthreads();
        if (w == 1) {
            float* rp = &red[lane * REDW];
#pragma unroll
            for (int ot = 0; ot < 4; ot++)
                *(float4*)&rp[ot * 4] = make_float4(accB[ot][0], accB[ot][1], accB[ot][2], accB[ot][3]);
        }
        __syncthreads();
        if (w == 0) {
            const float* rp = &red[lane * REDW];
#pragma unroll
            for (int ot = 0; ot < 4; ot++) {
                float4 v = *(const float4*)&rp[ot * 4];
                accB[ot][0] += v.x; accB[ot][1] += v.y;
                accB[ot][2] += v.z; accB[ot][3] += v.w;
            }
            int gp_m = gy * WW + gx0 + 16 + n;
#pragma unroll
            for (int ot = 0; ot < 4; ot++) {
                unsigned u0 = pkh(accB[ot][0], accB[ot][1]);
                unsigned u1 = pkh(accB[ot][2], accB[ot][3]);
                *(uint2*)&revH[gp_m * 64 + ot * 16 + q * 4] = make_uint2(u0, u1);
            }
        }
        return;
    }

    // ================= fft =================
    {
        short* sbf = (short*)smem_raw;                 // 9216 B
        short* e0H = (short*)(smem_raw + 64 * SROW * 2); // 9216 B

        int pb = b - 1152;
        int pbx = pb % 24, pby = pb / 24;
        int gx0 = pbx * 8, gy0 = pby * 8;

#pragma unroll
        for (int r = 0; r < 2; r++) {
            int idx = t + r * 256;             // 512 x 8-ch units
            int px = idx >> 3, g8 = idx & 7;
            int gy = gy0 + (px >> 3), gx = gx0 + (px & 7);
            *(uint4*)&sbf[px * SROW + g8 * 8] =
                *(const uint4*)&encH[(gy * WW + gx) * 64 + g8 * 8];
        }
        __syncthreads();

        int n = lane & 15, q = lane >> 4;
        h16x8 a0 = *(const h16x8*)&wpiA[(w * 2 + 0) * 512 + lane * 8];
        h16x8 a1 = *(const h16x8*)&wpiA[(w * 2 + 1) * 512 + lane * 8];
#pragma unroll
        for (int j = 0; j < 4; j++) {
            h16x8 b0 = *(const h16x8*)&sbf[(j * 16 + n) * SROW +  0 + q * 8];
            h16x8 b1 = *(const h16x8*)&sbf[(j * 16 + n) * SROW + 32 + q * 8];
            f32x4 acc = {0.f, 0.f, 0.f, 0.f};
            acc = __builtin_amdgcn_mfma_f32_16x16x32_f16(a0, b0, acc, 0, 0, 0);
            acc = __builtin_amdgcn_mfma_f32_16x16x32_f16(a1, b1, acc, 0, 0, 0);
            // f16 e0: lane writes ch w*16+q*4..+3 of px j*16+n
            unsigned u0 = pkh(acc[0], acc[1]);
            unsigned u1 = pkh(acc[2], acc[3]);
            *(unsigned*)&e0H[(j * 16 + n) * SROW + w * 16 + q * 4]     = u0;
            *(unsigned*)&e0H[(j * 16 + n) * SROW + w * 16 + q * 4 + 2] = u1;
        }
        __syncthreads();

        int o = t & 63;
        int yb = t >> 6;
#pragma unroll
        for (int yy = 0; yy < 2; yy++) {
            int y = yb + yy * 4;
            float outr[8];
#pragma unroll
            for (int x = 0; x < 8; x++) outr[x] = 0.f;
#pragma unroll
            for (int u = 0; u < 8; u++) {
                int ry = (y - u + 8) & 7;
                float row[8];
#pragma unroll
                for (int rx = 0; rx < 8; rx++)
                    row[rx] = h2f(((const unsigned short*)e0H)[(ry * 8 + rx) * SROW + o]);
#pragma unroll
                for (int v = 0; v < 8; v++) {
                    float kv = krT[(u * 8 + v) * 64 + o];
#pragma unroll
                    for (int x = 0; x < 8; x++)
                        outr[x] += kv * row[(x - v + 8) & 7];
                }
            }
            int gy = gy0 + y;
#pragma unroll
            for (int x = 0; x < 8; x++)
                e1H[(gy * WW + gx0 + x) * 64 + o] = f2h(outr[x]);
        }
    }
}

// ---------------------------------------------------------------------------
// k_c3out (R20): fused conv3x3(e1+rev, f16) -> [.,dec] -> proj_out ->
// SimpleGate with fully-coalesced dec reads and out writes.
// ---------------------------------------------------------------------------
__global__ __launch_bounds__(256) void k_c3out(
    const unsigned short* __restrict__ e1H, const unsigned short* __restrict__ revH,
    const short* __restrict__ w2A, const float* __restrict__ dec,
    const short* __restrict__ wpoA, float* __restrict__ out)
{
    __shared__ __align__(16) short sm[4][54 * C3ROW];  // 31104 B (per-wave stage)
    __shared__ __align__(16) unsigned decS[32 * 66];   //  8448 B (block-wide dec)
    int t = threadIdx.x;
    int lane = t & 63, w = t >> 6;
    int b = blockIdx.x;
    int xcd = b & 7, blk = b >> 3;
    int gy  = xcd * 24 + blk / 3;
    int gxb = (blk % 3) * 64;              // block px base
    int gx0 = gxb + w * 16;                // wave px base
    short* smw = &sm[w][0];
    int n = lane & 15, q = lane >> 4;
    int gpb = gy * WW + gxb;

    // ---- block-wide dec stage: full-line coalesced (64 px x 256B / plane) ----
    {
        int px = t & 63, cq = t >> 6;      // cq = w
#pragma unroll
        for (int r = 0; r < 8; r++) {
            int cp = cq + 4 * r;           // ch-pair 0..31
            int c0 = cp * 2;
            float v0 = dec[c0 * HWSZ + gpb + px];
            float v1 = dec[(c0 + 1) * HWSZ + gpb + px];
            decS[cp * 66 + px] = pkh(v0, v1);
        }
    }

    // ---- per-wave e1+rev halo stage ----
    for (int r = 0; r < 14; r++) {
        int u = lane + r * 64;
        if (u < 864) {
            int rp = u >> 4, g = u & 15;
            int row = rp / 18, pxl = rp - row * 18;
            int gyy = gy + row - 1, gxx = gx0 + pxl - 1;
            uint2 v = make_uint2(0u, 0u);
            if (gyy >= 0 && gyy < HH && gxx >= 0 && gxx < WW) {
                int gp = (gyy * WW + gxx) * 64 + g * 4;    // short index
                uint2 va = *(const uint2*)&e1H[gp];
                uint2 vb = *(const uint2*)&revH[gp];
                v.x = as_u(as_h2(va.x) + as_h2(vb.x));
                v.y = as_u(as_h2(va.y) + as_h2(vb.y));
            }
            *(uint2*)&smw[rp * C3ROW + g * 4] = v;
        }
    }
    __syncthreads();    // decS visible to all waves (smw is per-wave anyway)

    f32x4 acc[4];
#pragma unroll
    for (int ot = 0; ot < 4; ot++) acc[ot] = (f32x4){0.f, 0.f, 0.f, 0.f};

#pragma unroll 1
    for (int tap = 0; tap < 9; tap++) {
        int dy = tap / 3, dx = tap - dy * 3;
        int rp = dy * 18 + n + dx;
        h16x8 b0 = *(const h16x8*)&smw[rp * C3ROW +  0 + q * 8];
        h16x8 b1 = *(const h16x8*)&smw[rp * C3ROW + 32 + q * 8];
#pragma unroll
        for (int ot = 0; ot < 4; ot++) {
            h16x8 a0 = *(const h16x8*)&w2A[(tap * 8 + ot * 2 + 0) * 512 + lane * 8];
            h16x8 a1 = *(const h16x8*)&w2A[(tap * 8 + ot * 2 + 1) * 512 + lane * 8];
            acc[ot] = __builtin_amdgcn_mfma_f32_16x16x32_f16(a0, b0, acc[ot], 0, 0, 0);
            acc[ot] = __builtin_amdgcn_mfma_f32_16x16x32_f16(a1, b1, acc[ot], 0, 0, 0);
        }
    }

    // e3 (C-layout regs) -> B-frag rows in smw (shorts 0..63 per px)
#pragma unroll
    for (int ot = 0; ot < 4; ot++) {
        unsigned lo = pkh(acc[ot][0], acc[ot][1]);
        unsigned hi = pkh(acc[ot][2], acc[ot][3]);
        *(uint2*)&smw[n * OROW + ot * 16 + q * 4] = make_uint2(lo, hi);
    }

    f32x4 go[8];
#pragma unroll
    for (int ot = 0; ot < 8; ot++) go[ot] = (f32x4){0.f, 0.f, 0.f, 0.f};

#pragma unroll 1
    for (int kt = 0; kt < 4; kt++) {
        h16x8 bb;
        if (kt < 2) {
            bb = *(const h16x8*)&smw[n * OROW + kt * 32 + q * 8];
        } else {
            union { unsigned u[4]; h16x8 v; } tmp;
            int px = w * 16 + n;
            int cp0 = (kt - 2) * 16 + q * 4;
            tmp.u[0] = decS[(cp0 + 0) * 66 + px];
            tmp.u[1] = decS[(cp0 + 1) * 66 + px];
            tmp.u[2] = decS[(cp0 + 2) * 66 + px];
            tmp.u[3] = decS[(cp0 + 3) * 66 + px];
            bb = tmp.v;
        }
#pragma unroll
        for (int ot = 0; ot < 8; ot++) {
            h16x8 aa = *(const h16x8*)&wpoA[(ot * 4 + kt) * 512 + lane * 8];
            go[ot] = __builtin_amdgcn_mfma_f32_16x16x32_f16(aa, bb, go[ot], 0, 0, 0);
        }
    }

    // ---- SimpleGate -> outS[c][px] (reuse dead sm region) -> coalesced out ----
    __syncthreads();                       // all waves done reading smw
    float* outS = (float*)&sm[0][0];       // 64*66*4 = 16896 B <= 31104 B
#pragma unroll
    for (int ot = 0; ot < 4; ot++)
#pragma unroll
        for (int r = 0; r < 4; r++)
            outS[(ot * 16 + q * 4 + r) * 66 + w * 16 + n] = go[ot][r] * go[ot + 4][r];
    __syncthreads();
    {
        int px = t & 63;
#pragma unroll
        for (int r2 = 0; r2 < 16; r2++) {
            int c = (t >> 6) + 4 * r2;
            out[c * HWSZ + gpb + px] = outS[c * 66 + px];
        }
    }
}

// ---------------------------------------------------------------------------
extern "C" void kernel_launch(void* const* d_in, const int* in_sizes, int n_in,
                              void* d_out, int out_size, void* d_ws, size_t ws_size,
                              hipStream_t stream)
{
    const float* enc  = (const float*)d_in[0];
    const float* dec  = (const float*)d_in[1];
    const float* ioff = (const float*)d_in[2];
    const float* iwt  = (const float*)d_in[3];
    const float* wpi  = (const float*)d_in[4];
    const float* fw   = (const float*)d_in[5];
    const float* wpo  = (const float*)d_in[6];
    const float* wd   = (const float*)d_in[7];
    const float* wc1  = (const float*)d_in[8];
    const float* wc2  = (const float*)d_in[9];
    float* out = (float*)d_out;
    float* ws  = (float*)d_ws;

    float*          krT  = ws;                               //   4096 fl
    unsigned short* revH = (unsigned short*)(ws + 4096);     // 2359296 sh
    unsigned short* e1H  = (unsigned short*)(ws + 1183744);  // 2359296 sh
    unsigned short* encH = (unsigned short*)(ws + 2363392);  // 2359296 sh
    short*          wA   = (short*)(ws + 3543040);           // 200704 sh
    short*          w2A  = (short*)(ws + 3643392);           //  36864 sh
    short*          wpoA = (short*)(ws + 3661824);           //  16384 sh
    short*          wpiA = (short*)(ws + 3670016);           //   4096 sh

    hipLaunchKernelGGL(k_pt,    dim3(625),  dim3(256), 0, stream,
                       enc, encH, fw, wd, wc2, wc1, wpo, wpi, krT, wA, w2A, wpoA, wpiA);
    hipLaunchKernelGGL(k_dff,   dim3(1728), dim3(256), 0, stream,
                       encH, ioff, iwt, wA, revH, wpiA, krT, e1H);
    hipLaunchKernelGGL(k_c3out, dim3(576),  dim3(256), 0, stream,
                       e1H, revH, w2A, dec, wpoA, out);
}

// Round 16
// 186.834 us; speedup vs baseline: 3.2059x; 1.0024x over previous
//
#include <hip/hip_runtime.h>
#include <math.h>

#define CH    64
#define WW    192
#define HH    192
#define HWSZ  (192*192)
#define KK    49
#define ROWP  68   // padded fp32 LDS row (dwords)
#define SROW  72   // f16 row stride in shorts (144B)
#define C3ROW 72   // conv3 staged px stride (shorts)
#define OROW  136  // k_out staged px stride (shorts)
#define REDW  20   // reduction row stride (floats): 80B, 16B-aligned

typedef __attribute__((ext_vector_type(8))) short     s16x8;
typedef __attribute__((ext_vector_type(8))) _Float16  h16x8;  // 8 f16 = 4 VGPR
typedef __attribute__((ext_vector_type(2))) _Float16  h16x2;
typedef __attribute__((ext_vector_type(2))) __fp16    fp16x2; // cvt_pkrtz result type
typedef __attribute__((ext_vector_type(4))) float     f32x4;

__device__ __forceinline__ unsigned short f2h(float f) {
    union { _Float16 h; unsigned short s; } u; u.h = (_Float16)f;  // RNE
    return u.s;
}

__device__ __forceinline__ float h2f(unsigned short s) {
    union { unsigned short s; _Float16 h; } u; u.s = s;
    return (float)u.h;
}

// pack two floats to f16x2 (RTZ, single v_cvt_pkrtz_f16_f32)
__device__ __forceinline__ unsigned pkh(float lo, float hi) {
    union { fp16x2 h; unsigned u; } v;
    v.h = __builtin_amdgcn_cvt_pkrtz(lo, hi);
    return v.u;
}

// broadcast one float into packed f16x2 (for pk_fma weights)
__device__ __forceinline__ h16x2 cvt2h(float a) {
    union { fp16x2 h; h16x2 o; } v;
    v.h = __builtin_amdgcn_cvt_pkrtz(a, a);
    return v.o;
}

__device__ __forceinline__ h16x2 as_h2(unsigned u) {
    union { unsigned u; h16x2 h; } v; v.u = u; return v.h;
}

__device__ __forceinline__ unsigned as_u(h16x2 h) {
    union { h16x2 h; unsigned u; } v; v.h = h; return v.u;
}

// ---------------------------------------------------------------------------
// k_pt R22 (grid 576): every block does trans for its 64-px chunk; blocks
// 0..48 ALSO run prep (tap kb=b) afterwards (syncthreads + smem reuse).
// Removes the 49-block tail dispatch wavelet of the old grid-625 layout.
// ---------------------------------------------------------------------------
__device__ const float c_cos8[8] = {
    1.f, 0.70710678118654752f, 0.f, -0.70710678118654752f,
   -1.f, -0.70710678118654752f, 0.f, 0.70710678118654752f };

__global__ __launch_bounds__(256) void k_pt(
    const float* __restrict__ enc,  // trans input
    unsigned short* __restrict__ encH,
    const float* __restrict__ fw,   // [64,1,1,8,5]
    const float* __restrict__ wd,   // [64,64,7,7]
    const float* __restrict__ w2,   // [64,64,3,3]
    const float* __restrict__ wc1,  // [64,64,1,1]
    const float* __restrict__ wpo,  // [128,128]
    const float* __restrict__ wpi,  // [64,64]
    float* __restrict__ krT,        // [64 uv][64 c]
    short* __restrict__ wA,         // [49*8*512]
    short* __restrict__ w2A,        // [9*8*512]
    short* __restrict__ wpoA,       // [32*512]
    short* __restrict__ wpiA)       // [8*512]
{
    __shared__ __align__(16) char smem_raw[2 * 64 * ROWP * 4];  // 34816 B
    int b = blockIdx.x;
    int t = threadIdx.x;

    // ---- trans (all 576 blocks) ----
    {
        float* s = (float*)smem_raw;           // 64*65 floats = 16640 B
        int base = b * 64;
#pragma unroll
        for (int r = 0; r < 16; r++) {
            int idx = t + r * 256;
            int p = idx & 63, c = idx >> 6;
            s[p * 65 + c] = enc[c * HWSZ + base + p];
        }
        __syncthreads();
#pragma unroll
        for (int r = 0; r < 8; r++) {
            int idx = t + r * 256;             // 2048 pair-units
            int pr = idx & 31, p = idx >> 5;   // pair 0..31, px 0..63
            ((unsigned*)encH)[(base + p) * 32 + pr] =
                pkh(s[p * 65 + 2 * pr], s[p * 65 + 2 * pr + 1]);
        }
    }
    if (b >= 49) return;

    // ---- prep (blocks 0..48 continue) ----
    __syncthreads();                           // trans smem reads done
    int kb = b;                                // 0..48
    int tid = kb * 256 + t;
    int nt  = 49 * 256;
    for (int u = tid; u < 64 * 64; u += nt) {
        int uv = u >> 6, c = u & 63;
        int uu = uv >> 3, v = uv & 7;
        float acc = 0.f;
        for (int ky = 0; ky < 8; ky++)
            for (int kx = 0; kx < 8; kx++) {
                float wv = (kx <= 4) ? fw[c * 40 + ky * 5 + kx]
                                     : fw[c * 40 + ((8 - ky) & 7) * 5 + (8 - kx)];
                acc += wv * c_cos8[(ky * uu + kx * v) & 7];
            }
        krT[uv * 64 + c] = acc * (1.f / 64.f);
    }
    for (int u = tid; u < 9 * 4096; u += nt) {
        int tap = u / 4096, rem = u & 4095;
        int o = rem >> 6, c = rem & 63;
        float v = w2[(o * 64 + c) * 9 + tap];
        int fi = tap * 8 + (o >> 4) * 2 + (c >> 5);
        int ln = ((c >> 3) & 3) * 16 + (o & 15);
        w2A[fi * 512 + ln * 8 + (c & 7)] = (short)f2h(v);
    }
    for (int u = tid; u < 128 * 128; u += nt) {
        int o = u >> 7, c = u & 127;
        int fi = (o >> 4) * 4 + (c >> 5);
        int ln = ((c >> 3) & 3) * 16 + (o & 15);
        wpoA[fi * 512 + ln * 8 + (c & 7)] = (short)f2h(wpo[u]);
    }
    for (int u = tid; u < 64 * 64; u += nt) {
        int o = u >> 6, c = u & 63;
        int fi = (o >> 4) * 2 + (c >> 5);
        int ln = ((c >> 3) & 3) * 16 + (o & 15);
        wpiA[fi * 512 + ln * 8 + (c & 7)] = (short)f2h(wpi[u]);
    }

    // ---- fold wc1 @ wd + pack: one block per tap kb ----
    float* wdk  = (float*)smem_raw;            // 64*ROWP floats
    float* wc1s = wdk + 64 * ROWP;             // 64*ROWP floats
#pragma unroll
    for (int r = 0; r < 16; r++) {
        int idx = t + r * 256;
        int o = idx >> 6, c = idx & 63;
        wdk [o * ROWP + c] = wd[(o * 64 + c) * KK + kb];
        wc1s[o * ROWP + c] = wc1[o * 64 + c];
    }
    __syncthreads();

    int ot = (t >> 4) * 4, cb = (t & 15) * 4;
    float a[4][4];
#pragma unroll
    for (int i = 0; i < 4; i++)
#pragma unroll
        for (int j = 0; j < 4; j++) a[i][j] = 0.f;
    for (int o = 0; o < 64; o++) {
        float wv_[4], sv_[4];
#pragma unroll
        for (int i = 0; i < 4; i++) wv_[i] = wc1s[(ot + i) * ROWP + o];
#pragma unroll
        for (int j = 0; j < 4; j++) sv_[j] = wdk[o * ROWP + cb + j];
#pragma unroll
        for (int i = 0; i < 4; i++)
#pragma unroll
            for (int j = 0; j < 4; j++) a[i][j] += wv_[i] * sv_[j];
    }
#pragma unroll
    for (int i = 0; i < 4; i++)
#pragma unroll
        for (int j = 0; j < 4; j++) {
            int o2 = ot + i, c = cb + j;
            int tt = o2 >> 4, m = o2 & 15;
            int kt = c >> 5, q2 = (c >> 3) & 3, jj = c & 7;
            int ln = q2 * 16 + m;
            wA[(kb * 8 + tt * 2 + kt) * 512 + ln * 8 + jj] = (short)f2h(a[i][j]);
        }
}

// ---------------------------------------------------------------------------
// k_dff (grid 1728): b<1152 -> deform DUAL-STRIP (af[8] loaded once per tap,
// shared by both strips); b>=1152 -> fft. rev/e1 written f16 [px][64].
// ---------------------------------------------------------------------------
__global__ __launch_bounds__(256) void k_dff(
    const unsigned short* __restrict__ encH, const float* __restrict__ off,
    const float* __restrict__ msk, const short* __restrict__ wA,
    unsigned short* __restrict__ revH,
    const short* __restrict__ wpiA, const float* __restrict__ krT,
    unsigned short* __restrict__ e1H)
{
    __shared__ __align__(16) char smem_raw[28672];
    int t = threadIdx.x;
    int lane = t & 63, w = t >> 6;
    int b = blockIdx.x;

    if (b < 1152) {
        // ================= deform (dual-strip) =================
        short* sm_base = (short*)smem_raw;                   // 4 x 32*SROW shorts = 18432
        float* red = (float*)(smem_raw + 4 * 32 * SROW * 2); // 2*64*REDW floats = 10240

        int xcd = b & 7, blk = b >> 3;          // 144 strip-pairs per xcd band
        int gy  = xcd * 24 + blk / 6;
        int gx0 = (blk % 6) * 32;               // strip A at gx0, strip B at gx0+16

        int sp = lane >> 2, g = lane & 3;       // gather map: quad-coalesced
        int sgxA = gx0 + sp,       sgxB = gx0 + 16 + sp;
        int gpA  = gy * WW + sgxA, gpB  = gy * WW + sgxB;
        int n = lane & 15, q = lane >> 4;       // B-frag read map
        short* smw = sm_base + w * (32 * SROW);

        f32x4 accA[4], accB[4];
#pragma unroll
        for (int ot = 0; ot < 4; ot++) {
            accA[ot] = (f32x4){0.f, 0.f, 0.f, 0.f};
            accB[ot] = (f32x4){0.f, 0.f, 0.f, 0.f};
        }

        int kstart = (w == 0) ? 0 : 13 + (w - 1) * 12;
        int kend   = (w == 0) ? 13 : kstart + 12;

        float dyA = off[(2 * kstart) * HWSZ + gpA];
        float dxA = off[(2 * kstart + 1) * HWSZ + gpA];
        float mmA = msk[kstart * HWSZ + gpA];
        float dyB = off[(2 * kstart) * HWSZ + gpB];
        float dxB = off[(2 * kstart + 1) * HWSZ + gpB];
        float mmB = msk[kstart * HWSZ + gpB];

#pragma unroll 1
        for (int k = kstart; k < kend; k++) {
            int ky = k / 7, kx = k % 7;

            // ---- strip A setup + gather ----
            float yA = (float)(gy - 3 + ky) + dyA;
            float xA = (float)(sgxA - 3 + kx) + dxA;
            float y0fA = floorf(yA), x0fA = floorf(xA);
            float wyA = yA - y0fA, wxA = xA - x0fA;
            int iy0A = (int)y0fA, ix0A = (int)x0fA;
            int iy1A = iy0A + 1, ix1A = ix0A + 1;
            bool vy0A = (iy0A >= 0) & (iy0A < HH);
            bool vy1A = (iy1A >= 0) & (iy1A < HH);
            bool vx0A = (ix0A >= 0) & (ix0A < WW);
            bool vx1A = (ix1A >= 0) & (ix1A < WW);
            int iy0cA = min(max(iy0A, 0), HH - 1), iy1cA = min(max(iy1A, 0), HH - 1);
            int ix0cA = min(max(ix0A, 0), WW - 1), ix1cA = min(max(ix1A, 0), WW - 1);
            float a00A = (vy0A & vx0A) ? (1.f - wyA) * (1.f - wxA) * mmA : 0.f;
            float a01A = (vy0A & vx1A) ? (1.f - wyA) * wxA * mmA : 0.f;
            float a10A = (vy1A & vx0A) ? wyA * (1.f - wxA) * mmA : 0.f;
            float a11A = (vy1A & vx1A) ? wyA * wxA * mmA : 0.f;

            const unsigned short* pA00 = encH + (iy0cA * WW + ix0cA) * 64 + g * 16;
            const unsigned short* pA01 = encH + (iy0cA * WW + ix1cA) * 64 + g * 16;
            const unsigned short* pA10 = encH + (iy1cA * WW + ix0cA) * 64 + g * 16;
            const unsigned short* pA11 = encH + (iy1cA * WW + ix1cA) * 64 + g * 16;
            uint4 uA00[2], uA01[2], uA10[2], uA11[2];
            uA00[0] = *(const uint4*)pA00;  uA00[1] = *(const uint4*)(pA00 + 8);
            uA01[0] = *(const uint4*)pA01;  uA01[1] = *(const uint4*)(pA01 + 8);
            uA10[0] = *(const uint4*)pA10;  uA10[1] = *(const uint4*)(pA10 + 8);
            uA11[0] = *(const uint4*)pA11;  uA11[1] = *(const uint4*)(pA11 + 8);

            // ---- A-frags: ONE load per tap, shared by both strips ----
            h16x8 af[8];
#pragma unroll
            for (int f = 0; f < 8; f++)
                af[f] = *(const h16x8*)&wA[(k * 8 + f) * 512 + lane * 8];

            // ---- strip A blend + bounce + MFMA ----
            {
                h16x2 w00 = cvt2h(a00A), w01 = cvt2h(a01A);
                h16x2 w10 = cvt2h(a10A), w11 = cvt2h(a11A);
                unsigned c00[8] = {uA00[0].x, uA00[0].y, uA00[0].z, uA00[0].w,
                                   uA00[1].x, uA00[1].y, uA00[1].z, uA00[1].w};
                unsigned c01[8] = {uA01[0].x, uA01[0].y, uA01[0].z, uA01[0].w,
                                   uA01[1].x, uA01[1].y, uA01[1].z, uA01[1].w};
                unsigned c10[8] = {uA10[0].x, uA10[0].y, uA10[0].z, uA10[0].w,
                                   uA10[1].x, uA10[1].y, uA10[1].z, uA10[1].w};
                unsigned c11[8] = {uA11[0].x, uA11[0].y, uA11[0].z, uA11[0].w,
                                   uA11[1].x, uA11[1].y, uA11[1].z, uA11[1].w};
                unsigned pk[8];
#pragma unroll
                for (int j = 0; j < 8; j++) {
                    h16x2 r = as_h2(c00[j]) * w00;
                    r = as_h2(c01[j]) * w01 + r;
                    r = as_h2(c10[j]) * w10 + r;
                    r = as_h2(c11[j]) * w11 + r;
                    pk[j] = as_u(r);
                }
                *(uint4*)&smw[sp * SROW + g * 16]     = make_uint4(pk[0], pk[1], pk[2], pk[3]);
                *(uint4*)&smw[sp * SROW + g * 16 + 8] = make_uint4(pk[4], pk[5], pk[6], pk[7]);

                h16x8 b0 = *(const h16x8*)&smw[n * SROW +  0 + q * 8];
                h16x8 b1 = *(const h16x8*)&smw[n * SROW + 32 + q * 8];
#pragma unroll
                for (int ot = 0; ot < 4; ot++) {
                    accA[ot] = __builtin_amdgcn_mfma_f32_16x16x32_f16(af[ot * 2],     b0, accA[ot], 0, 0, 0);
                    accA[ot] = __builtin_amdgcn_mfma_f32_16x16x32_f16(af[ot * 2 + 1], b1, accA[ot], 0, 0, 0);
                }
            }

            // ---- strip B setup + gather (after A consumed: bounded VGPR) ----
            float yB = (float)(gy - 3 + ky) + dyB;
            float xB = (float)(sgxB - 3 + kx) + dxB;
            float y0fB = floorf(yB), x0fB = floorf(xB);
            float wyB = yB - y0fB, wxB = xB - x0fB;
            int iy0B = (int)y0fB, ix0B = (int)x0fB;
            int iy1B = iy0B + 1, ix1B = ix0B + 1;
            bool vy0B = (iy0B >= 0) & (iy0B < HH);
            bool vy1B = (iy1B >= 0) & (iy1B < HH);
            bool vx0B = (ix0B >= 0) & (ix0B < WW);
            bool vx1B = (ix1B >= 0) & (ix1B < WW);
            int iy0cB = min(max(iy0B, 0), HH - 1), iy1cB = min(max(iy1B, 0), HH - 1);
            int ix0cB = min(max(ix0B, 0), WW - 1), ix1cB = min(max(ix1B, 0), WW - 1);
            float a00B = (vy0B & vx0B) ? (1.f - wyB) * (1.f - wxB) * mmB : 0.f;
            float a01B = (vy0B & vx1B) ? (1.f - wyB) * wxB * mmB : 0.f;
            float a10B = (vy1B & vx0B) ? wyB * (1.f - wxB) * mmB : 0.f;
            float a11B = (vy1B & vx1B) ? wyB * wxB * mmB : 0.f;

            const unsigned short* pB00 = encH + (iy0cB * WW + ix0cB) * 64 + g * 16;
            const unsigned short* pB01 = encH + (iy0cB * WW + ix1cB) * 64 + g * 16;
            const unsigned short* pB10 = encH + (iy1cB * WW + ix0cB) * 64 + g * 16;
            const unsigned short* pB11 = encH + (iy1cB * WW + ix1cB) * 64 + g * 16;
            uint4 uB00[2], uB01[2], uB10[2], uB11[2];
            uB00[0] = *(const uint4*)pB00;  uB00[1] = *(const uint4*)(pB00 + 8);
            uB01[0] = *(const uint4*)pB01;  uB01[1] = *(const uint4*)(pB01 + 8);
            uB10[0] = *(const uint4*)pB10;  uB10[1] = *(const uint4*)(pB10 + 8);
            uB11[0] = *(const uint4*)pB11;  uB11[1] = *(const uint4*)(pB11 + 8);

            // prefetch next-tap offsets (both strips)
            if (k + 1 < kend) {
                dyA = off[(2 * k + 2) * HWSZ + gpA];
                dxA = off[(2 * k + 3) * HWSZ + gpA];
                mmA = msk[(k + 1) * HWSZ + gpA];
                dyB = off[(2 * k + 2) * HWSZ + gpB];
                dxB = off[(2 * k + 3) * HWSZ + gpB];
                mmB = msk[(k + 1) * HWSZ + gpB];
            }

            // ---- strip B blend + bounce + MFMA (rows 16+) ----
            {
                h16x2 w00 = cvt2h(a00B), w01 = cvt2h(a01B);
                h16x2 w10 = cvt2h(a10B), w11 = cvt2h(a11B);
                unsigned c00[8] = {uB00[0].x, uB00[0].y, uB00[0].z, uB00[0].w,
                                   uB00[1].x, uB00[1].y, uB00[1].z, uB00[1].w};
                unsigned c01[8] = {uB01[0].x, uB01[0].y, uB01[0].z, uB01[0].w,
                                   uB01[1].x, uB01[1].y, uB01[1].z, uB01[1].w};
                unsigned c10[8] = {uB10[0].x, uB10[0].y, uB10[0].z, uB10[0].w,
                                   uB10[1].x, uB10[1].y, uB10[1].z, uB10[1].w};
                unsigned c11[8] = {uB11[0].x, uB11[0].y, uB11[0].z, uB11[0].w,
                                   uB11[1].x, uB11[1].y, uB11[1].z, uB11[1].w};
                unsigned pk[8];
#pragma unroll
                for (int j = 0; j < 8; j++) {
                    h16x2 r = as_h2(c00[j]) * w00;
                    r = as_h2(c01[j]) * w01 + r;
                    r = as_h2(c10[j]) * w10 + r;
                    r = as_h2(c11[j]) * w11 + r;
                    pk[j] = as_u(r);
                }
                *(uint4*)&smw[(16 + sp) * SROW + g * 16]     = make_uint4(pk[0], pk[1], pk[2], pk[3]);
                *(uint4*)&smw[(16 + sp) * SROW + g * 16 + 8] = make_uint4(pk[4], pk[5], pk[6], pk[7]);

                h16x8 b0 = *(const h16x8*)&smw[(16 + n) * SROW +  0 + q * 8];
                h16x8 b1 = *(const h16x8*)&smw[(16 + n) * SROW + 32 + q * 8];
#pragma unroll
                for (int ot = 0; ot < 4; ot++) {
                    accB[ot] = __builtin_amdgcn_mfma_f32_16x16x32_f16(af[ot * 2],     b0, accB[ot], 0, 0, 0);
                    accB[ot] = __builtin_amdgcn_mfma_f32_16x16x32_f16(af[ot * 2 + 1], b1, accB[ot], 0, 0, 0);
                }
            }
        }

        // ---- strip A reduction + write ----
        if (w >= 2) {
            float* rp = &red[((w - 2) * 64 + lane) * REDW];
#pragma unroll
            for (int ot = 0; ot < 4; ot++)
                *(float4*)&rp[ot * 4] = make_float4(accA[ot][0], accA[ot][1], accA[ot][2], accA[ot][3]);
        }
        __syncthreads();
        if (w < 2) {
            const float* rp = &red[(w * 64 + lane) * REDW];
#pragma unroll
            for (int ot = 0; ot < 4; ot++) {
                float4 v = *(const float4*)&rp[ot * 4];
                accA[ot][0] += v.x; accA[ot][1] += v.y;
                accA[ot][2] += v.z; accA[ot][3] += v.w;
            }
        }
        __syncthreads();
        if (w == 1) {
            float* rp = &red[lane * REDW];
#pragma unroll
            for (int ot = 0; ot < 4; ot++)
                *(float4*)&rp[ot * 4] = make_float4(accA[ot][0], accA[ot][1], accA[ot][2], accA[ot][3]);
        }
        __syncthreads();
        if (w == 0) {
            const float* rp = &red[lane * REDW];
#pragma unroll
            for (int ot = 0; ot < 4; ot++) {
                float4 v = *(const float4*)&rp[ot * 4];
                accA[ot][0] += v.x; accA[ot][1] += v.y;
                accA[ot][2] += v.z; accA[ot][3] += v.w;
            }
            int gp_m = gy * WW + gx0 + n;
#pragma unroll
            for (int ot = 0; ot < 4; ot++) {
                unsigned u0 = pkh(accA[ot][0], accA[ot][1]);
                unsigned u1 = pkh(accA[ot][2], accA[ot][3]);
                *(uint2*)&revH[gp_m * 64 + ot * 16 + q * 4] = make_uint2(u0, u1);
            }
        }
        __syncthreads();

        // ---- strip B reduction + write ----
        if (w >= 2) {
            float* rp = &red[((w - 2) * 64 + lane) * REDW];
#pragma unroll
            for (int ot = 0; ot < 4; ot++)
                *(float4*)&rp[ot * 4] = make_float4(accB[ot][0], accB[ot][1], accB[ot][2], accB[ot][3]);
        }
        __syncthreads();
        if (w < 2) {
            const float* rp = &red[(w * 64 + lane) * REDW];
#pragma unroll
            for (int ot = 0; ot < 4; ot++) {
                float4 v = *(const float4*)&rp[ot * 4];
                accB[ot][0] += v.x; accB[ot][1] += v.y;
                accB[ot][2] += v.z; accB[ot][3] += v.w;
            }
        }
        __syncthreads();
        if (w == 1) {
            float* rp = &red[lane * REDW];
#pragma unroll
            for (int ot = 0; ot < 4; ot++)
                *(float4*)&rp[ot * 4] = make_float4(accB[ot][0], accB[ot][1], accB[ot][2], accB[ot][3]);
        }
        __syncthreads();
        if (w == 0) {
            const float* rp = &red[lane * REDW];
#pragma unroll
            for (int ot = 0; ot < 4; ot++) {
                float4 v = *(const float4*)&rp[ot * 4];
                accB[ot][0] += v.x; accB[ot][1] += v.y;
                accB[ot][2] += v.z; accB[ot][3] += v.w;
            }
            int gp_m = gy * WW + gx0 + 16 + n;
#pragma unroll
            for (int ot = 0; ot < 4; ot++) {
                unsigned u0 = pkh(accB[ot][0], accB[ot][1]);
                unsigned u1 = pkh(accB[ot][2], accB[ot][3]);
                *(uint2*)&revH[gp_m * 64 + ot * 16 + q * 4] = make_uint2(u0, u1);
            }
        }
        return;
    }

    // ================= fft =================
    {
        short* sbf = (short*)smem_raw;                 // 9216 B
        short* e0H = (short*)(smem_raw + 64 * SROW * 2); // 9216 B

        int pb = b - 1152;
        int pbx = pb % 24, pby = pb / 24;
        int gx0 = pbx * 8, gy0 = pby * 8;

#pragma unroll
        for (int r = 0; r < 2; r++) {
            int idx = t + r * 256;             // 512 x 8-ch units
            int px = idx >> 3, g8 = idx & 7;
            int gy = gy0 + (px >> 3), gx = gx0 + (px & 7);
            *(uint4*)&sbf[px * SROW + g8 * 8] =
                *(const uint4*)&encH[(gy * WW + gx) * 64 + g8 * 8];
        }
        __syncthreads();

        int n = lane & 15, q = lane >> 4;
        h16x8 a0 = *(const h16x8*)&wpiA[(w * 2 + 0) * 512 + lane * 8];
        h16x8 a1 = *(const h16x8*)&wpiA[(w * 2 + 1) * 512 + lane * 8];
#pragma unroll
        for (int j = 0; j < 4; j++) {
            h16x8 b0 = *(const h16x8*)&sbf[(j * 16 + n) * SROW +  0 + q * 8];
            h16x8 b1 = *(const h16x8*)&sbf[(j * 16 + n) * SROW + 32 + q * 8];
            f32x4 acc = {0.f, 0.f, 0.f, 0.f};
            acc = __builtin_amdgcn_mfma_f32_16x16x32_f16(a0, b0, acc, 0, 0, 0);
            acc = __builtin_amdgcn_mfma_f32_16x16x32_f16(a1, b1, acc, 0, 0, 0);
            // f16 e0: lane writes ch w*16+q*4..+3 of px j*16+n
            unsigned u0 = pkh(acc[0], acc[1]);
            unsigned u1 = pkh(acc[2], acc[3]);
            *(unsigned*)&e0H[(j * 16 + n) * SROW + w * 16 + q * 4]     = u0;
            *(unsigned*)&e0H[(j * 16 + n) * SROW + w * 16 + q * 4 + 2] = u1;
        }
        __syncthreads();

        int o = t & 63;
        int yb = t >> 6;
#pragma unroll
        for (int yy = 0; yy < 2; yy++) {
            int y = yb + yy * 4;
            float outr[8];
#pragma unroll
            for (int x = 0; x < 8; x++) outr[x] = 0.f;
#pragma unroll
            for (int u = 0; u < 8; u++) {
                int ry = (y - u + 8) & 7;
                float row[8];
#pragma unroll
                for (int rx = 0; rx < 8; rx++)
                    row[rx] = h2f(((const unsigned short*)e0H)[(ry * 8 + rx) * SROW + o]);
#pragma unroll
                for (int v = 0; v < 8; v++) {
                    float kv = krT[(u * 8 + v) * 64 + o];
#pragma unroll
                    for (int x = 0; x < 8; x++)
                        outr[x] += kv * row[(x - v + 8) & 7];
                }
            }
            int gy = gy0 + y;
#pragma unroll
            for (int x = 0; x < 8; x++)
                e1H[(gy * WW + gx0 + x) * 64 + o] = f2h(outr[x]);
        }
    }
}

// ---------------------------------------------------------------------------
// k_c3out (R20): fused conv3x3(e1+rev, f16) -> [.,dec] -> proj_out ->
// SimpleGate with fully-coalesced dec reads and out writes.
// ---------------------------------------------------------------------------
__global__ __launch_bounds__(256) void k_c3out(
    const unsigned short* __restrict__ e1H, const unsigned short* __restrict__ revH,
    const short* __restrict__ w2A, const float* __restrict__ dec,
    const short* __restrict__ wpoA, float* __restrict__ out)
{
    __shared__ __align__(16) short sm[4][54 * C3ROW];  // 31104 B (per-wave stage)
    __shared__ __align__(16) unsigned decS[32 * 66];   //  8448 B (block-wide dec)
    int t = threadIdx.x;
    int lane = t & 63, w = t >> 6;
    int b = blockIdx.x;
    int xcd = b & 7, blk = b >> 3;
    int gy  = xcd * 24 + blk / 3;
    int gxb = (blk % 3) * 64;              // block px base
    int gx0 = gxb + w * 16;                // wave px base
    short* smw = &sm[w][0];
    int n = lane & 15, q = lane >> 4;
    int gpb = gy * WW + gxb;

    // ---- block-wide dec stage: full-line coalesced (64 px x 256B / plane) ----
    {
        int px = t & 63, cq = t >> 6;      // cq = w
#pragma unroll
        for (int r = 0; r < 8; r++) {
            int cp = cq + 4 * r;           // ch-pair 0..31
            int c0 = cp * 2;
            float v0 = dec[c0 * HWSZ + gpb + px];
            float v1 = dec[(c0 + 1) * HWSZ + gpb + px];
            decS[cp * 66 + px] = pkh(v0, v1);
        }
    }

    // ---- per-wave e1+rev halo stage ----
    for (int r = 0; r < 14; r++) {
        int u = lane + r * 64;
        if (u < 864) {
            int rp = u >> 4, g = u & 15;
            int row = rp / 18, pxl = rp - row * 18;
            int gyy = gy + row - 1, gxx = gx0 + pxl - 1;
            uint2 v = make_uint2(0u, 0u);
            if (gyy >= 0 && gyy < HH && gxx >= 0 && gxx < WW) {
                int gp = (gyy * WW + gxx) * 64 + g * 4;    // short index
                uint2 va = *(const uint2*)&e1H[gp];
                uint2 vb = *(const uint2*)&revH[gp];
                v.x = as_u(as_h2(va.x) + as_h2(vb.x));
                v.y = as_u(as_h2(va.y) + as_h2(vb.y));
            }
            *(uint2*)&smw[rp * C3ROW + g * 4] = v;
        }
    }
    __syncthreads();    // decS visible to all waves (smw is per-wave anyway)

    f32x4 acc[4];
#pragma unroll
    for (int ot = 0; ot < 4; ot++) acc[ot] = (f32x4){0.f, 0.f, 0.f, 0.f};

#pragma unroll 1
    for (int tap = 0; tap < 9; tap++) {
        int dy = tap / 3, dx = tap - dy * 3;
        int rp = dy * 18 + n + dx;
        h16x8 b0 = *(const h16x8*)&smw[rp * C3ROW +  0 + q * 8];
        h16x8 b1 = *(const h16x8*)&smw[rp * C3ROW + 32 + q * 8];
#pragma unroll
        for (int ot = 0; ot < 4; ot++) {
            h16x8 a0 = *(const h16x8*)&w2A[(tap * 8 + ot * 2 + 0) * 512 + lane * 8];
            h16x8 a1 = *(const h16x8*)&w2A[(tap * 8 + ot * 2 + 1) * 512 + lane * 8];
            acc[ot] = __builtin_amdgcn_mfma_f32_16x16x32_f16(a0, b0, acc[ot], 0, 0, 0);
            acc[ot] = __builtin_amdgcn_mfma_f32_16x16x32_f16(a1, b1, acc[ot], 0, 0, 0);
        }
    }

    // e3 (C-layout regs) -> B-frag rows in smw (shorts 0..63 per px)
#pragma unroll
    for (int ot = 0; ot < 4; ot++) {
        unsigned lo = pkh(acc[ot][0], acc[ot][1]);
        unsigned hi = pkh(acc[ot][2], acc[ot][3]);
        *(uint2*)&smw[n * OROW + ot * 16 + q * 4] = make_uint2(lo, hi);
    }

    f32x4 go[8];
#pragma unroll
    for (int ot = 0; ot < 8; ot++) go[ot] = (f32x4){0.f, 0.f, 0.f, 0.f};

#pragma unroll 1
    for (int kt = 0; kt < 4; kt++) {
        h16x8 bb;
        if (kt < 2) {
            bb = *(const h16x8*)&smw[n * OROW + kt * 32 + q * 8];
        } else {
            union { unsigned u[4]; h16x8 v; } tmp;
            int px = w * 16 + n;
            int cp0 = (kt - 2) * 16 + q * 4;
            tmp.u[0] = decS[(cp0 + 0) * 66 + px];
            tmp.u[1] = decS[(cp0 + 1) * 66 + px];
            tmp.u[2] = decS[(cp0 + 2) * 66 + px];
            tmp.u[3] = decS[(cp0 + 3) * 66 + px];
            bb = tmp.v;
        }
#pragma unroll
        for (int ot = 0; ot < 8; ot++) {
            h16x8 aa = *(const h16x8*)&wpoA[(ot * 4 + kt) * 512 + lane * 8];
            go[ot] = __builtin_amdgcn_mfma_f32_16x16x32_f16(aa, bb, go[ot], 0, 0, 0);
        }
    }

    // ---- SimpleGate -> outS[c][px] (reuse dead sm region) -> coalesced out ----
    __syncthreads();                       // all waves done reading smw
    float* outS = (float*)&sm[0][0];       // 64*66*4 = 16896 B <= 31104 B
#pragma unroll
    for (int ot = 0; ot < 4; ot++)
#pragma unroll
        for (int r = 0; r < 4; r++)
            outS[(ot * 16 + q * 4 + r) * 66 + w * 16 + n] = go[ot][r] * go[ot + 4][r];
    __syncthreads();
    {
        int px = t & 63;
#pragma unroll
        for (int r2 = 0; r2 < 16; r2++) {
            int c = (t >> 6) + 4 * r2;
            out[c * HWSZ + gpb + px] = outS[c * 66 + px];
        }
    }
}

// ---------------------------------------------------------------------------
extern "C" void kernel_launch(void* const* d_in, const int* in_sizes, int n_in,
                              void* d_out, int out_size, void* d_ws, size_t ws_size,
                              hipStream_t stream)
{
    const float* enc  = (const float*)d_in[0];
    const float* dec  = (const float*)d_in[1];
    const float* ioff = (const float*)d_in[2];
    const float* iwt  = (const float*)d_in[3];
    const float* wpi  = (const float*)d_in[4];
    const float* fw   = (const float*)d_in[5];
    const float* wpo  = (const float*)d_in[6];
    const float* wd   = (const float*)d_in[7];
    const float* wc1  = (const float*)d_in[8];
    const float* wc2  = (const float*)d_in[9];
    float* out = (float*)d_out;
    float* ws  = (float*)d_ws;

    float*          krT  = ws;                               //   4096 fl
    unsigned short* revH = (unsigned short*)(ws + 4096);     // 2359296 sh
    unsigned short* e1H  = (unsigned short*)(ws + 1183744);  // 2359296 sh
    unsigned short* encH = (unsigned short*)(ws + 2363392);  // 2359296 sh
    short*          wA   = (short*)(ws + 3543040);           // 200704 sh
    short*          w2A  = (short*)(ws + 3643392);           //  36864 sh
    short*          wpoA = (short*)(ws + 3661824);           //  16384 sh
    short*          wpiA = (short*)(ws + 3670016);           //   4096 sh

    hipLaunchKernelGGL(k_pt,    dim3(576),  dim3(256), 0, stream,
                       enc, encH, fw, wd, wc2, wc1, wpo, wpi, krT, wA, w2A, wpoA, wpiA);
    hipLaunchKernelGGL(k_dff,   dim3(1728), dim3(256), 0, stream,
                       encH, ioff, iwt, wA, revH, wpiA, krT, e1H);
    hipLaunchKernelGGL(k_c3out, dim3(576),  dim3(256), 0, stream,
                       e1H, revH, w2A, dec, wpoA, out);
}